// Round 7
// baseline (1965.004 us; speedup 1.0000x reference)
//
#include <hip/hip_runtime.h>
#include <math.h>

#define NRR 175
#define KK 250
#define NN (NRR*KK)

#define S0_0 56
#define S0_1 350
#define S0_2 512
#define S1_0 28
#define S1_1 175
#define S1_2 256
#define S2_0 14
#define S2_1 88
#define S2_2 128
#define CAP1 350000
#define CAP2 69000
#define C1 32
#define C2 128
#define FOP 69632   // fo_t row stride (padded)
#define NB2X 69120  // 540*128, level-2 nb table stride

#define CELLS0 (S0_0*S0_1*S0_2)   // 10035200
#define CELLS1 (S1_0*S1_1*S1_2)   // 1254400
#define CELLS2 (S2_0*S2_1*S2_2)   // 157696

#define ATT_SCALE 0.17677669529663687f

typedef __attribute__((ext_vector_type(8))) __bf16 bf16x8;
typedef __attribute__((ext_vector_type(16))) float f32x16;

// ---------- bf16 helpers (RNE) ----------
__device__ __forceinline__ unsigned short f2b(float x) {
    unsigned int u = __builtin_bit_cast(unsigned int, x);
    unsigned int r = u + 0x7FFFu + ((u >> 16) & 1u);
    return (unsigned short)(r >> 16);
}
__device__ __forceinline__ float b2f(unsigned short h) {
    return __builtin_bit_cast(float, (unsigned int)h << 16);
}

// XCD-contiguous block swizzle (kept: cut FETCH 55->31 MB in R5)
__device__ __forceinline__ int xcd_swizzle(int b, int nx) {
    int per = nx >> 3, rem = nx & 7;
    int x = b & 7, i = b >> 3;
    return x * per + min(x, rem) + i;
}

// ---------- helpers ----------
__device__ __forceinline__ int block_incl_scan(int v, int* s) {
    int t = threadIdx.x;
    s[t] = v; __syncthreads();
    #pragma unroll
    for (int d = 1; d < 256; d <<= 1) {
        int x = (t >= d) ? s[t - d] : 0;
        __syncthreads();
        s[t] += x;
        __syncthreads();
    }
    return s[t];
}

__device__ __forceinline__ void cand(int p, int So, int* o, int& no) {
    no = 0;
    if ((p & 1) == 0) {
        int q = p >> 1; if (q < So) o[no++] = q;
    } else {
        int q = (p - 1) >> 1; if (q < So) o[no++] = q;
        q = (p + 1) >> 1;     if (q < So) o[no++] = q;
    }
}

// ---------- stage kernels ----------
__global__ __launch_bounds__(256) void k_init(const float* __restrict__ vf,
                                              const int* __restrict__ coors,
                                              float* __restrict__ x,
                                              int* __restrict__ lut0,
                                              int* __restrict__ om1) {
    int i = blockIdx.x * 256 + threadIdx.x;
    if (i >= NN) return;
    x[i] = log10f(vf[i * 2]);
    int c1 = coors[i * 4 + 1], c2 = coors[i * 4 + 2], c3 = coors[i * 4 + 3];
    int e = 2 * c1 - 9, rg = 2 * c2, az = 2 * c3 + 149;
    atomicMax(&lut0[(e * S0_1 + rg) * S0_2 + az], i);
    int A[2], B[2], C[2]; int na, nb, nc;
    cand(e, S1_0, A, na); cand(rg, S1_1, B, nb); cand(az, S1_2, C, nc);
    for (int ia = 0; ia < na; ia++)
        for (int ib = 0; ib < nb; ib++)
            for (int ic = 0; ic < nc; ic++)
                om1[(A[ia] * S1_1 + B[ib]) * S1_2 + C[ic]] = 1;
}

// ---------- MFMA attention ----------
#define QS 40
__global__ __launch_bounds__(256, 1) void k_attn(float* __restrict__ x_io,
    const int* __restrict__ coors,
    const float* __restrict__ et, const float* __restrict__ at,
    const float* __restrict__ wq, const float* __restrict__ bq,
    const float* __restrict__ wk, const float* __restrict__ bk,
    const float* __restrict__ wv, const float* __restrict__ bv) {
    __shared__ float xin[KK * 7];
    __shared__ unsigned short ksh_h[256 * QS];
    __shared__ unsigned short ksh_l[256 * QS];
    __shared__ float vsh[256];
    const int r = blockIdx.x;
    const int t = threadIdx.x;
    const int w = t >> 6, ln = t & 63, l31 = ln & 31, lh = ln >> 5;

    for (int i = t; i < KK; i += 256) {
        int gi = r * KK + i;
        xin[i * 7 + 0] = x_io[gi];
        int c1 = coors[gi * 4 + 1], c3 = coors[gi * 4 + 3];
        xin[i * 7 + 1] = et[c1 * 3 + 0]; xin[i * 7 + 2] = et[c1 * 3 + 1]; xin[i * 7 + 3] = et[c1 * 3 + 2];
        xin[i * 7 + 4] = at[c3 * 3 + 0]; xin[i * 7 + 5] = at[c3 * 3 + 1]; xin[i * 7 + 6] = at[c3 * 3 + 2];
    }
    __syncthreads();

    union U8 { bf16x8 v; unsigned short u[8]; };

    for (int l = 0; l < 4; l++) {
        const float* wql = wq + l * 7 * 32; const float* bql = bq + l * 32;
        const float* wkl = wk + l * 7 * 32; const float* bkl = bk + l * 32;
        const float* wvl = wv + l * 7;      const float  bvl = bv[l];
        float qh_f[32], ql_f[32];
        if (t < KK) {
            float xi[7];
            #pragma unroll
            for (int ci = 0; ci < 7; ci++) xi[ci] = xin[t * 7 + ci];
            float av = bvl;
            #pragma unroll
            for (int ci = 0; ci < 7; ci++) av += xi[ci] * wvl[ci];
            vsh[t] = av;
            #pragma unroll
            for (int d = 0; d < 32; d++) {
                float aq = bql[d], ak = bkl[d];
                #pragma unroll
                for (int ci = 0; ci < 7; ci++) { aq += xi[ci] * wql[ci * 32 + d]; ak += xi[ci] * wkl[ci * 32 + d]; }
                aq *= ATT_SCALE;
                float h = b2f(f2b(aq));
                qh_f[d] = h; ql_f[d] = aq - h;
                unsigned short k16 = f2b(ak);
                ksh_h[t * QS + d] = k16;
                ksh_l[t * QS + d] = f2b(ak - b2f(k16));
            }
        } else {
            #pragma unroll
            for (int d = 0; d < 32; d++) {
                qh_f[d] = 0.f; ql_f[d] = 0.f;
                ksh_h[t * QS + d] = 0; ksh_l[t * QS + d] = 0;
            }
            vsh[t] = 0.f;
        }
        __syncthreads();

        U8 Bh[2][2], Bl[2][2];
        #pragma unroll
        for (int b = 0; b < 2; b++) {
            int src = b * 32 + l31;
            #pragma unroll
            for (int ks = 0; ks < 2; ks++) {
                #pragma unroll
                for (int j = 0; j < 8; j++) {
                    float h0 = __shfl(qh_f[ks * 16 + j],     src, 64);
                    float h1 = __shfl(qh_f[ks * 16 + 8 + j], src, 64);
                    float l0 = __shfl(ql_f[ks * 16 + j],     src, 64);
                    float l1 = __shfl(ql_f[ks * 16 + 8 + j], src, 64);
                    Bh[b][ks].u[j] = f2b(lh ? h1 : h0);
                    Bl[b][ks].u[j] = f2b(lh ? l1 : l0);
                }
            }
        }

        float m[2]  = {-1e30f, -1e30f};
        float den[2] = {0.f, 0.f};
        float num[2] = {0.f, 0.f};

        for (int mt = 0; mt < 8; mt++) {
            U8 Ah[2], Al[2];
            int krow = mt * 32 + l31;
            #pragma unroll
            for (int ks = 0; ks < 2; ks++) {
                Ah[ks].v = *(const bf16x8*)&ksh_h[krow * QS + ks * 16 + lh * 8];
                Al[ks].v = *(const bf16x8*)&ksh_l[krow * QS + ks * 16 + lh * 8];
            }
            float4 v4[4];
            #pragma unroll
            for (int c = 0; c < 4; c++)
                v4[c] = *(const float4*)&vsh[mt * 32 + 8 * c + 4 * lh];

            #pragma unroll
            for (int b = 0; b < 2; b++) {
                f32x16 acc;
                #pragma unroll
                for (int q = 0; q < 16; q++) acc[q] = 0.f;
                acc = __builtin_amdgcn_mfma_f32_32x32x16_bf16(Ah[0].v, Bh[b][0].v, acc, 0, 0, 0);
                acc = __builtin_amdgcn_mfma_f32_32x32x16_bf16(Ah[1].v, Bh[b][1].v, acc, 0, 0, 0);
                acc = __builtin_amdgcn_mfma_f32_32x32x16_bf16(Ah[0].v, Bl[b][0].v, acc, 0, 0, 0);
                acc = __builtin_amdgcn_mfma_f32_32x32x16_bf16(Ah[1].v, Bl[b][1].v, acc, 0, 0, 0);
                acc = __builtin_amdgcn_mfma_f32_32x32x16_bf16(Al[0].v, Bh[b][0].v, acc, 0, 0, 0);
                acc = __builtin_amdgcn_mfma_f32_32x32x16_bf16(Al[1].v, Bh[b][1].v, acc, 0, 0, 0);

                float s[16];
                #pragma unroll
                for (int rr = 0; rr < 16; rr++) {
                    s[rr] = acc[rr];
                    if (mt == 7) {
                        int key = 224 + (rr & 3) + 8 * (rr >> 2) + 4 * lh;
                        if (key >= KK) s[rr] = -1e30f;
                    }
                }
                float cm = s[0];
                #pragma unroll
                for (int rr = 1; rr < 16; rr++) cm = fmaxf(cm, s[rr]);
                cm = fmaxf(cm, __shfl_xor(cm, 32, 64));
                float mn = fmaxf(m[b], cm);
                float alpha = __expf(m[b] - mn);
                float dsum = 0.f, nsum = 0.f;
                #pragma unroll
                for (int rr = 0; rr < 16; rr++) {
                    float e = __expf(s[rr] - mn);
                    dsum += e;
                    nsum += e * ((&v4[rr >> 2].x)[rr & 3]);
                }
                den[b] = den[b] * alpha + dsum;
                num[b] = num[b] * alpha + nsum;
                m[b] = mn;
            }
        }
        __syncthreads();
        #pragma unroll
        for (int b = 0; b < 2; b++) {
            float dtot = den[b] + __shfl_xor(den[b], 32, 64);
            float ntot = num[b] + __shfl_xor(num[b], 32, 64);
            int q = (w * 2 + b) * 32 + l31;
            if (lh == 0 && q < KK) xin[q * 7] = ntot / dtot;
        }
        __syncthreads();
    }
    for (int i = t; i < KK; i += 256) x_io[r * KK + i] = xin[i * 7];
}

__global__ __launch_bounds__(256) void k_f0(const int* __restrict__ coors,
    const float* __restrict__ x,
    const float* __restrict__ w_in, const float* __restrict__ b_in,
    const float* __restrict__ gg, const float* __restrict__ gb,
    unsigned short* __restrict__ f0) {
    int i = blockIdx.x * 256 + threadIdx.x;
    if (i >= NN) return;
    int c1 = coors[i * 4 + 1], c2 = coors[i * 4 + 2], c3 = coors[i * 4 + 3];
    float fe0 = (float)(2 * c1 - 9), fe1 = (float)(2 * c2), fe2 = (float)(2 * c3 + 149), fe3 = x[i];
    float tv[16];
    #pragma unroll
    for (int c = 0; c < 16; c++)
        tv[c] = b_in[c] + fe0 * w_in[c] + fe1 * w_in[16 + c] + fe2 * w_in[32 + c] + fe3 * w_in[48 + c];
    #pragma unroll
    for (int g = 0; g < 8; g++) {
        float a = tv[2 * g], b = tv[2 * g + 1];
        float m = 0.5f * (a + b);
        float va = 0.5f * ((a - m) * (a - m) + (b - m) * (b - m));
        float inv = rsqrtf(va + 1e-5f);
        f0[i * 16 + 2 * g]     = f2b(fmaxf((a - m) * inv * gg[2 * g]     + gb[2 * g],     0.f));
        f0[i * 16 + 2 * g + 1] = f2b(fmaxf((b - m) * inv * gg[2 * g + 1] + gb[2 * g + 1], 0.f));
    }
}

__global__ __launch_bounds__(256) void k_blocksum(const int* __restrict__ om,
                                                  int* __restrict__ partials, int ncells) {
    __shared__ int sh[256];
    int t = threadIdx.x;
    int base = blockIdx.x * 1024 + t * 4;
    int s = 0;
    #pragma unroll
    for (int q = 0; q < 4; q++) s += (base + q < ncells) ? om[base + q] : 0;
    int incl = block_incl_scan(s, sh);
    if (t == 255) partials[blockIdx.x] = incl;
}

__global__ __launch_bounds__(256) void k_scanparts(int* __restrict__ partials, int nparts,
                                                   int* __restrict__ pcnt, int cap) {
    __shared__ int sh[256];
    __shared__ int tot;
    int t = threadIdx.x;
    int chunk = (nparts + 255) / 256;
    int beg = t * chunk;
    int vals[8];
    int s = 0;
    #pragma unroll
    for (int i = 0; i < 8; i++) {
        if (i < chunk) {
            int ix = beg + i;
            int x = (ix < nparts) ? partials[ix] : 0;
            vals[i] = x; s += x;
        }
    }
    int incl = block_incl_scan(s, sh);
    int excl = incl - s;
    if (t == 255) tot = incl;
    int run = excl;
    #pragma unroll
    for (int i = 0; i < 8; i++) {
        if (i < chunk) {
            int ix = beg + i;
            if (ix < nparts) { partials[ix] = run; run += vals[i]; }
        }
    }
    __syncthreads();
    if (t == 0) *pcnt = min(tot, cap);
}

__global__ __launch_bounds__(256) void k_emit(const int* __restrict__ om,
                                              const int* __restrict__ partials,
                                              int* __restrict__ oc,
                                              int ncells, int D1, int D2, int cap) {
    __shared__ int sh[256];
    int t = threadIdx.x;
    int base = blockIdx.x * 1024 + t * 4;
    int v[4]; int s = 0;
    #pragma unroll
    for (int q = 0; q < 4; q++) { v[q] = (base + q < ncells) ? om[base + q] : 0; s += v[q]; }
    int incl = block_incl_scan(s, sh);
    int run = partials[blockIdx.x] + (incl - s);
    int D12 = D1 * D2;
    #pragma unroll
    for (int q = 0; q < 4; q++) {
        if (v[q]) {
            if (run < cap) {
                int lin = base + q;
                int i0 = lin / D12;
                int r2 = lin - i0 * D12;
                int i1 = r2 / D2;
                int i2 = r2 - i1 * D2;
                oc[run * 3] = i0; oc[run * 3 + 1] = i1; oc[run * 3 + 2] = i2;
            }
            run++;
        }
    }
}

__global__ __launch_bounds__(256) void k_lutscatter(const int* __restrict__ oc,
                                                    const int* __restrict__ pc,
                                                    int* __restrict__ lut, int D1, int D2) {
    int j = blockIdx.x * 256 + threadIdx.x;
    if (j >= *pc) return;
    lut[(oc[j * 3] * D1 + oc[j * 3 + 1]) * D2 + oc[j * 3 + 2]] = j;
}

__global__ __launch_bounds__(256) void k_lutscatter2(const int* __restrict__ oc,
                                                     const int* __restrict__ pc,
                                                     int* __restrict__ lut,
                                                     int* __restrict__ lut_t) {
    int j = blockIdx.x * 256 + threadIdx.x;
    if (j >= *pc) return;
    int a = oc[j * 3], b = oc[j * 3 + 1], c = oc[j * 3 + 2];
    lut[(a * S2_1 + b) * S2_2 + c] = j;
    lut_t[(c * S2_1 + b) * S2_0 + a] = j;
}

__global__ __launch_bounds__(256) void k_mask2(const int* __restrict__ oc,
                                               const int* __restrict__ pc,
                                               int* __restrict__ om) {
    int j = blockIdx.x * 256 + threadIdx.x;
    if (j >= *pc) return;
    int p0 = oc[j * 3], p1 = oc[j * 3 + 1], p2 = oc[j * 3 + 2];
    int A[2], B[2], C[2]; int na, nb, nc;
    cand(p0, S2_0, A, na); cand(p1, S2_1, B, nb); cand(p2, S2_2, C, nc);
    for (int ia = 0; ia < na; ia++)
        for (int ib = 0; ib < nb; ib++)
            for (int ic = 0; ic < nc; ic++)
                om[(A[ia] * S2_1 + B[ib]) * S2_2 + C[ic]] = 1;
}

// ---------- weight pre-pack into MFMA B-fragment order ----------
__global__ __launch_bounds__(256) void k_prepack(const float* __restrict__ w,
        unsigned short* __restrict__ wp, int nk, int cin, int cout) {
    int tid = blockIdx.x * 256 + threadIdx.x;
    int tot = nk * cin * cout;
    if (tid >= tot) return;
    int co = tid % cout; int rest = tid / cout; int ci = rest % cin; int kk = rest / cin;
    int ks = ci >> 4, kr = ci & 15, half = kr >> 3, j = kr & 7;
    int nt = co >> 5, cl = co & 31, lane = half * 32 + cl;
    wp[((((size_t)kk * (cin >> 4) + ks) * (cout >> 5) + nt) * 64 + lane) * 8 + j] = f2b(w[tid]);
}

// ---------- neighbor-index table (level 2): nb[k][j] = gather row or ZR ----------
template<bool DOWN, int SD0, int SD1, int SD2>
__global__ __launch_bounds__(256) void k_nbidx(const int* __restrict__ oc,
        const int* __restrict__ pc, const int* __restrict__ lut,
        int* __restrict__ nb, int NBx, int ZR) {
    int gid = blockIdx.x * 256 + threadIdx.x;
    if (gid >= 27 * NBx) return;
    int k = gid / NBx, j = gid - k * NBx;
    int idx = ZR;
    if (j < *pc) {
        int dx = k / 9 - 1, dy = (k / 3) % 3 - 1, dz = k % 3 - 1;
        int x = oc[j * 3], y = oc[j * 3 + 1], z = oc[j * 3 + 2];
        if (DOWN) { x = 2 * x + dx; y = 2 * y + dy; z = 2 * z + dz; }
        else      { x += dx; y += dy; z += dz; }
        if ((unsigned)x < (unsigned)SD0 && (unsigned)y < (unsigned)SD1 && (unsigned)z < (unsigned)SD2) {
            int v = lut[(x * SD1 + y) * SD2 + z];
            if (v >= 0) idx = v;
        }
    }
    nb[gid] = idx;
}

// ---------- LDS-staged MFMA gather-conv, line-coalesced staging ----------
// 128 rows x COUT per block, 256 threads = 4 waves.
// COUT=128: wave w owns cols w*32..+31, ALL 128 rows (TM=4, B read once/block).
// COUT=32:  wave w owns rows w*32..+31, all 32 cols (TM=1).
// STAGING (the R7 fix): CPR consecutive lanes cover ALL chunks of ONE row
// (contiguous bytes -> 1-2 cache-line transactions per row instead of 1 per
// 16B chunk). Thread t, sweep s: row = t/CPR + s*(256/CPR), chunk = t%CPR.
// Gather rows come from precomputed nb table (TAB=1, level 2) or inline lut
// (TAB=0, level 1; 1-2 lookups/thread, lanes sharing a row dedupe in TA).
// Register prefetch: next k-step's rows load during current MFMA section.
// MODE 0: bn+relu  MODE 1: bn+res+relu  MODE 2: bias+gn16+relu -> fo_t
template<int CIN, int COUT, int SD0, int SD1, int SD2, bool DOWN, int MODE, bool TAB>
__global__ __launch_bounds__(256)
void k_sconv(const unsigned short* __restrict__ fin, const int* __restrict__ lut,
             const int* __restrict__ nb, int NBx,
             const int* __restrict__ oc, const int* __restrict__ pc,
             const unsigned short* __restrict__ wp,
             const float* __restrict__ p0, const float* __restrict__ p1,
             const float* __restrict__ p2,
             const unsigned short* __restrict__ res, void* __restrict__ fout_,
             int ZR) {
    constexpr int KS   = CIN / 16;
    constexpr int NTT  = COUT / 32;
    constexpr int TM   = (COUT == 128) ? 4 : 1;
    constexpr int SROW = CIN + 8;
    constexpr int CPR  = CIN / 8;          // 16B chunks per row
    constexpr int RPS  = 256 / CPR;        // rows per sweep
    constexpr int SW   = 128 / RPS;        // sweeps ( = CPR/2 )
    __shared__ unsigned short sA[128 * SROW];

    const int n = *pc;
    const int blk = xcd_swizzle(blockIdx.x, gridDim.x);
    const int j0 = blk * 128;
    if (j0 >= n) return;
    const int t = threadIdx.x;
    const int w = t >> 6, ln = t & 63, l31 = ln & 31, lh = ln >> 5;
    const int rowb = (COUT == 128) ? 0 : w * 32;
    const int colt = (COUT == 128) ? w : 0;

    const int brow = t / CPR;              // base staging row
    const int chnk = t % CPR;
    const uint4* fin4 = (const uint4*)fin;

    // coords for inline-lut mode (one row per sweep)
    int cx[SW], cy[SW], cz[SW];
    if (!TAB) {
        #pragma unroll
        for (int s = 0; s < SW; s++) {
            int j = j0 + brow + s * RPS;
            if (j < n) { cx[s] = oc[j * 3]; cy[s] = oc[j * 3 + 1]; cz[s] = oc[j * 3 + 2]; }
            else       { cx[s] = -1000000; cy[s] = -1000000; cz[s] = -1000000; }
        }
    }

    auto fetchIdx = [&](int kk, int* ir) {
        if (TAB) {
            #pragma unroll
            for (int s = 0; s < SW; s++)
                ir[s] = nb[kk * NBx + j0 + brow + s * RPS];
        } else {
            int dx = kk / 9 - 1, dy = (kk / 3) % 3 - 1, dz = kk % 3 - 1;
            #pragma unroll
            for (int s = 0; s < SW; s++) {
                int x, y, z;
                if (DOWN) { x = 2 * cx[s] + dx; y = 2 * cy[s] + dy; z = 2 * cz[s] + dz; }
                else      { x = cx[s] + dx; y = cy[s] + dy; z = cz[s] + dz; }
                int idx = -1;
                if ((unsigned)x < (unsigned)SD0 && (unsigned)y < (unsigned)SD1 && (unsigned)z < (unsigned)SD2)
                    idx = lut[(x * SD1 + y) * SD2 + z];
                ir[s] = idx < 0 ? ZR : idx;
            }
        }
    };

    uint4 ld[SW];
    auto loadAll = [&](const int* ir) {
        #pragma unroll
        for (int s = 0; s < SW; s++)
            ld[s] = fin4[(size_t)ir[s] * CPR + chnk];
    };

    f32x16 acc[TM];
    #pragma unroll
    for (int a = 0; a < TM; a++)
        #pragma unroll
        for (int q = 0; q < 16; q++) acc[a][q] = 0.f;

    int ir0[SW], ir1[SW];
    fetchIdx(0, ir0);
    loadAll(ir0);
    fetchIdx(1, ir1);

    for (int k = 0; k < 27; k++) {
        __syncthreads();
        #pragma unroll
        for (int s = 0; s < SW; s++)
            *(uint4*)&sA[(brow + s * RPS) * SROW + chnk * 8] = ld[s];
        __syncthreads();
        if (k < 26) {
            loadAll(ir1);                         // gather for k+1, in flight over MFMAs
            fetchIdx(k + 2 <= 26 ? k + 2 : 26, ir1);
        }
        const unsigned short* wk = wp + (size_t)k * KS * NTT * 512;
        bf16x8 breg[KS];
        #pragma unroll
        for (int ks = 0; ks < KS; ks++)
            breg[ks] = *(const bf16x8*)(wk + ((size_t)(ks * NTT + colt) * 64 + ln) * 8);
        #pragma unroll
        for (int ks = 0; ks < KS; ks++) {
            #pragma unroll
            for (int a = 0; a < TM; a++) {
                bf16x8 afr = *(const bf16x8*)(&sA[(rowb + a * 32 + l31) * SROW + ks * 16 + lh * 8]);
                acc[a] = __builtin_amdgcn_mfma_f32_32x32x16_bf16(afr, breg[ks], acc[a], 0, 0, 0);
            }
        }
    }

    const int co = colt * 32 + l31;
    if (MODE != 2) {
        unsigned short* fout = (unsigned short*)fout_;
        float g_ = p0[co], bb_ = p0[COUT + co], m_ = p0[2 * COUT + co];
        float iv = rsqrtf(p0[3 * COUT + co] + 1e-3f);
        #pragma unroll
        for (int a = 0; a < TM; a++) {
            #pragma unroll
            for (int r = 0; r < 16; r++) {
                int j = j0 + rowb + a * 32 + (r & 3) + 8 * (r >> 2) + 4 * lh;
                if (j < n) {
                    float y = (acc[a][r] - m_) * iv * g_ + bb_;
                    if (MODE == 1) y += b2f(res[(size_t)j * COUT + co]);
                    fout[(size_t)j * COUT + co] = f2b(fmaxf(y, 0.f));
                }
            }
        }
    } else {
        float* fo_t = (float*)fout_;
        float bias = p0[co], gg_ = p1[co], gb_ = p2[co];
        #pragma unroll
        for (int a = 0; a < TM; a++) {
            #pragma unroll
            for (int r = 0; r < 16; r++) {
                int j = j0 + rowb + a * 32 + (r & 3) + 8 * (r >> 2) + 4 * lh;
                float y = acc[a][r] + bias;
                float s = y;
                s += __shfl_xor(s, 1, 8);
                s += __shfl_xor(s, 2, 8);
                s += __shfl_xor(s, 4, 8);
                float m = s * 0.125f;
                float d = y - m;
                float q2 = d * d;
                q2 += __shfl_xor(q2, 1, 8);
                q2 += __shfl_xor(q2, 2, 8);
                q2 += __shfl_xor(q2, 4, 8);
                float var = q2 * 0.125f;
                float o = fmaxf(d * rsqrtf(var + 1e-5f) * gg_ + gb_, 0.f);
                fo_t[(size_t)co * FOP + j] = o;
            }
        }
    }
}

// ---------- dense output scatter (coalesced reads AND writes) ----------
__global__ __launch_bounds__(256) void k_scatter(const float* __restrict__ fo_t,
                                                 const int* __restrict__ lut2t,
                                                 float* __restrict__ dout) {
    int gid = blockIdx.x * 256 + threadIdx.x;
    int cell = gid % CELLS2;
    int co = gid / CELLS2;
    int idx = lut2t[cell];
    float v = 0.f;
    if (idx >= 0) v = fo_t[(size_t)co * FOP + idx];
    dout[gid] = v;
}

// ---------- host ----------
extern "C" void kernel_launch(void* const* d_in, const int* in_sizes, int n_in,
                              void* d_out, int out_size, void* d_ws, size_t ws_size,
                              hipStream_t stream) {
    const float* vf    = (const float*)d_in[0];
    const int*   coors = (const int*)d_in[1];
    const float* et    = (const float*)d_in[3];
    const float* at    = (const float*)d_in[4];
    const float* wq    = (const float*)d_in[5];
    const float* bq    = (const float*)d_in[6];
    const float* wk_   = (const float*)d_in[7];
    const float* bk    = (const float*)d_in[8];
    const float* wv    = (const float*)d_in[9];
    const float* bv    = (const float*)d_in[10];
    const float* w_in  = (const float*)d_in[11];
    const float* b_in  = (const float*)d_in[12];
    const float* gin_g = (const float*)d_in[13];
    const float* gin_b = (const float*)d_in[14];
    const float* w_d1  = (const float*)d_in[15];
    const float* bn_d1 = (const float*)d_in[16];
    const float* w_r1  = (const float*)d_in[17];
    const float* bn_r1 = (const float*)d_in[18];
    const float* w_d2  = (const float*)d_in[19];
    const float* bn_d2 = (const float*)d_in[20];
    const float* w_r2  = (const float*)d_in[21];
    const float* bn_r2 = (const float*)d_in[22];
    const float* w_out = (const float*)d_in[23];
    const float* b_out = (const float*)d_in[24];
    const float* gout_g= (const float*)d_in[25];
    const float* gout_b= (const float*)d_in[26];

    char* ws = (char*)d_ws;
    size_t cur = 0;
    auto take = [&](size_t bytes) -> char* {
        char* p = ws + cur;
        cur += (bytes + 255) & ~(size_t)255;
        return p;
    };
    size_t usz1 = (size_t)4194304 + (size_t)CELLS0 * 4;
    size_t usz2 = (size_t)17694720 + (size_t)128 * FOP * 4;
    char* U = take(usz1 > usz2 ? usz1 : usz2);
    float*          x_att = (float*)U;
    unsigned short* f0    = (unsigned short*)(U + 262144);
    int*            lut0  = (int*)(U + 4194304);
    unsigned short* fB1   = (unsigned short*)U;
    unsigned short* fA2   = (unsigned short*)U;
    unsigned short* fB2   = (unsigned short*)(U + 17694720);
    float*          fo_t  = (float*)(U + 17694720);

    int*   om1      = (int*)take((size_t)CELLS1 * 4);
    int*   om2      = (int*)take((size_t)CELLS2 * 4);
    int*   partials = (int*)take(8192);
    int*   cnt      = (int*)take(256);
    int*   oc1      = (int*)take((size_t)CAP1 * 3 * 4);
    int*   oc2      = (int*)take((size_t)CAP2 * 3 * 4);
    unsigned short* fA1 = (unsigned short*)take((size_t)(CAP1 + 1) * C1 * 2);
    int*   lut1     = (int*)take((size_t)CELLS1 * 4);
    int*   lut2     = (int*)take((size_t)CELLS2 * 4);
    int*   lut2t    = (int*)take((size_t)CELLS2 * 4);
    int*   nb_d2    = (int*)take((size_t)27 * NB2X * 4);
    int*   nb_r2    = (int*)take((size_t)27 * NB2X * 4);
    unsigned short* wp_d1  = (unsigned short*)take((size_t)27 * 16 * 32 * 2);
    unsigned short* wp_r1  = (unsigned short*)take((size_t)108 * 32 * 32 * 2);
    unsigned short* wp_d2  = (unsigned short*)take((size_t)27 * 32 * 128 * 2);
    unsigned short* wp_r2  = (unsigned short*)take((size_t)108 * 128 * 128 * 2);
    unsigned short* wp_out = (unsigned short*)take((size_t)27 * 128 * 128 * 2);

    hipMemsetAsync(lut0, 0xFF, (size_t)CELLS0 * 4, stream);
    hipMemsetAsync(om1, 0, (size_t)CELLS1 * 4, stream);
    hipMemsetAsync(om2, 0, (size_t)CELLS2 * 4, stream);
    hipMemsetAsync(lut1, 0xFF, (size_t)CELLS1 * 4, stream);
    hipMemsetAsync(lut2, 0xFF, (size_t)CELLS2 * 4, stream);
    hipMemsetAsync(lut2t, 0xFF, (size_t)CELLS2 * 4, stream);
    hipMemsetAsync(f0 + (size_t)NN * 16, 0, 32, stream);        // f0 zero row (ZR=NN)
    hipMemsetAsync(fA1 + (size_t)CAP1 * C1, 0, 64, stream);     // fA1 zero row (ZR=CAP1)

    const int gN  = (NN + 255) / 256;
    const int gB1 = CELLS1 / 1024;
    const int gB2 = CELLS2 / 1024;
    const int gM1 = (CAP1 + 127) / 128;   // 2735
    const int gM2 = (CAP2 + 127) / 128;   // 540
    const int gS1 = (CAP1 + 255) / 256;
    const int gS2 = (CAP2 + 255) / 256;
    const int gNB = (27 * NB2X + 255) / 256;

    k_prepack<<<(27*16*32   + 255)/256, 256, 0, stream>>>(w_d1,  wp_d1, 27, 16, 32);
    k_prepack<<<(108*32*32  + 255)/256, 256, 0, stream>>>(w_r1,  wp_r1, 108, 32, 32);
    k_prepack<<<(27*32*128  + 255)/256, 256, 0, stream>>>(w_d2,  wp_d2, 27, 32, 128);
    k_prepack<<<(108*128*128+ 255)/256, 256, 0, stream>>>(w_r2,  wp_r2, 108, 128, 128);
    k_prepack<<<(27*128*128 + 255)/256, 256, 0, stream>>>(w_out, wp_out, 27, 128, 128);

    k_init<<<gN, 256, 0, stream>>>(vf, coors, x_att, lut0, om1);
    k_attn<<<NRR, 256, 0, stream>>>(x_att, coors, et, at, wq, bq, wk_, bk, wv, bv);
    k_f0<<<gN, 256, 0, stream>>>(coors, x_att, w_in, b_in, gin_g, gin_b, f0);

    k_blocksum<<<gB1, 256, 0, stream>>>(om1, partials, CELLS1);
    k_scanparts<<<1, 256, 0, stream>>>(partials, gB1, cnt, CAP1);
    k_emit<<<gB1, 256, 0, stream>>>(om1, partials, oc1, CELLS1, S1_1, S1_2, CAP1);

    // down conv 1 (16 -> 32), inline lut0
    k_sconv<16, 32, S0_0, S0_1, S0_2, true, 0, false><<<gM1, 256, 0, stream>>>(
        f0, lut0, nullptr, 0, oc1, cnt, wp_d1, bn_d1, nullptr, nullptr, nullptr, fA1, NN);
    k_lutscatter<<<gS1, 256, 0, stream>>>(oc1, cnt, lut1, S1_1, S1_2);
    hipMemsetAsync(fB1 + (size_t)CAP1 * C1, 0, 64, stream);     // fB1 zero row (lut0 dead)

    // resblocks level 1 (32 ch), inline lut1
    k_sconv<32, 32, S1_0, S1_1, S1_2, false, 0, false><<<gM1, 256, 0, stream>>>(
        fA1, lut1, nullptr, 0, oc1, cnt, wp_r1 + 0 * 27648, bn_r1 + 0 * 128, nullptr, nullptr, nullptr, fB1, CAP1);
    k_sconv<32, 32, S1_0, S1_1, S1_2, false, 1, false><<<gM1, 256, 0, stream>>>(
        fB1, lut1, nullptr, 0, oc1, cnt, wp_r1 + 1 * 27648, bn_r1 + 1 * 128, nullptr, nullptr, fA1, fA1, CAP1);
    k_sconv<32, 32, S1_0, S1_1, S1_2, false, 0, false><<<gM1, 256, 0, stream>>>(
        fA1, lut1, nullptr, 0, oc1, cnt, wp_r1 + 2 * 27648, bn_r1 + 2 * 128, nullptr, nullptr, nullptr, fB1, CAP1);
    k_sconv<32, 32, S1_0, S1_1, S1_2, false, 1, false><<<gM1, 256, 0, stream>>>(
        fB1, lut1, nullptr, 0, oc1, cnt, wp_r1 + 3 * 27648, bn_r1 + 3 * 128, nullptr, nullptr, fA1, fA1, CAP1);

    k_mask2<<<gS1, 256, 0, stream>>>(oc1, cnt, om2);
    k_blocksum<<<gB2, 256, 0, stream>>>(om2, partials, CELLS2);
    k_scanparts<<<1, 256, 0, stream>>>(partials, gB2, cnt + 1, CAP2);
    k_emit<<<gB2, 256, 0, stream>>>(om2, partials, oc2, CELLS2, S2_1, S2_2, CAP2);

    // level-2 neighbor tables + zero rows
    k_nbidx<true, S1_0, S1_1, S1_2><<<gNB, 256, 0, stream>>>(oc2, cnt + 1, lut1, nb_d2, NB2X, CAP1);
    hipMemsetAsync(fA2 + (size_t)CAP2 * C2, 0, 256, stream);
    hipMemsetAsync(fB2 + (size_t)CAP2 * C2, 0, 256, stream);

    // down conv 2 (32 -> 128), nb table
    k_sconv<32, 128, S1_0, S1_1, S1_2, true, 0, true><<<gM2, 256, 0, stream>>>(
        fA1, nullptr, nb_d2, NB2X, oc2, cnt + 1, wp_d2, bn_d2, nullptr, nullptr, nullptr, fA2, CAP1);
    k_lutscatter2<<<gS2, 256, 0, stream>>>(oc2, cnt + 1, lut2, lut2t);
    k_nbidx<false, S2_0, S2_1, S2_2><<<gNB, 256, 0, stream>>>(oc2, cnt + 1, lut2, nb_r2, NB2X, CAP2);

    const size_t wr2s = (size_t)27 * 128 * 128;
    k_sconv<128, 128, S2_0, S2_1, S2_2, false, 0, true><<<gM2, 256, 0, stream>>>(
        fA2, nullptr, nb_r2, NB2X, oc2, cnt + 1, wp_r2 + 0 * wr2s, bn_r2 + 0 * 512, nullptr, nullptr, nullptr, fB2, CAP2);
    k_sconv<128, 128, S2_0, S2_1, S2_2, false, 1, true><<<gM2, 256, 0, stream>>>(
        fB2, nullptr, nb_r2, NB2X, oc2, cnt + 1, wp_r2 + 1 * wr2s, bn_r2 + 1 * 512, nullptr, nullptr, fA2, fA2, CAP2);
    k_sconv<128, 128, S2_0, S2_1, S2_2, false, 0, true><<<gM2, 256, 0, stream>>>(
        fA2, nullptr, nb_r2, NB2X, oc2, cnt + 1, wp_r2 + 2 * wr2s, bn_r2 + 2 * 512, nullptr, nullptr, nullptr, fB2, CAP2);
    k_sconv<128, 128, S2_0, S2_1, S2_2, false, 1, true><<<gM2, 256, 0, stream>>>(
        fB2, nullptr, nb_r2, NB2X, oc2, cnt + 1, wp_r2 + 3 * wr2s, bn_r2 + 3 * 512, nullptr, nullptr, fA2, fA2, CAP2);

    k_sconv<128, 128, S2_0, S2_1, S2_2, false, 2, true><<<gM2, 256, 0, stream>>>(
        fA2, nullptr, nb_r2, NB2X, oc2, cnt + 1, wp_out, b_out, gout_g, gout_b, nullptr, fo_t, CAP2);
    k_scatter<<<(S2_0 * S2_1 * S2_2 * 128) / 256, 256, 0, stream>>>(fo_t, lut2t, (float*)d_out);
}

// Round 8
// 1329.494 us; speedup vs baseline: 1.4780x; 1.4780x over previous
//
#include <hip/hip_runtime.h>
#include <math.h>

#define NRR 175
#define KK 250
#define NN (NRR*KK)

#define S0_0 56
#define S0_1 350
#define S0_2 512
#define S1_0 28
#define S1_1 175
#define S1_2 256
#define S2_0 14
#define S2_1 88
#define S2_2 128
#define CAP1 350000
#define CAP2 69000
#define C1 32
#define C2 128
#define FOP 69632   // fo_t row stride (padded)
#define NB2X 69120  // 540*128, level-2 nb table stride

#define CELLS0 (S0_0*S0_1*S0_2)   // 10035200
#define CELLS1 (S1_0*S1_1*S1_2)   // 1254400
#define CELLS2 (S2_0*S2_1*S2_2)   // 157696

#define ATT_SCALE 0.17677669529663687f

typedef __attribute__((ext_vector_type(8))) __bf16 bf16x8;
typedef __attribute__((ext_vector_type(16))) float f32x16;

typedef __attribute__((address_space(3))) unsigned int       lds_u32;
typedef const __attribute__((address_space(1))) unsigned int glb_u32;

// async global->LDS, 16B per lane, LDS dest = wave-uniform base + lane*16
__device__ __forceinline__ void gld_lds16(unsigned short* lds_base, const unsigned short* gptr) {
    __builtin_amdgcn_global_load_lds((glb_u32*)gptr, (lds_u32*)lds_base, 16, 0, 0);
}

// ---------- bf16 helpers (RNE) ----------
__device__ __forceinline__ unsigned short f2b(float x) {
    unsigned int u = __builtin_bit_cast(unsigned int, x);
    unsigned int r = u + 0x7FFFu + ((u >> 16) & 1u);
    return (unsigned short)(r >> 16);
}
__device__ __forceinline__ float b2f(unsigned short h) {
    return __builtin_bit_cast(float, (unsigned int)h << 16);
}

// XCD-contiguous block swizzle
__device__ __forceinline__ int xcd_swizzle(int b, int nx) {
    int per = nx >> 3, rem = nx & 7;
    int x = b & 7, i = b >> 3;
    return x * per + min(x, rem) + i;
}

// ---------- helpers ----------
__device__ __forceinline__ int block_incl_scan(int v, int* s) {
    int t = threadIdx.x;
    s[t] = v; __syncthreads();
    #pragma unroll
    for (int d = 1; d < 256; d <<= 1) {
        int x = (t >= d) ? s[t - d] : 0;
        __syncthreads();
        s[t] += x;
        __syncthreads();
    }
    return s[t];
}

__device__ __forceinline__ void cand(int p, int So, int* o, int& no) {
    no = 0;
    if ((p & 1) == 0) {
        int q = p >> 1; if (q < So) o[no++] = q;
    } else {
        int q = (p - 1) >> 1; if (q < So) o[no++] = q;
        q = (p + 1) >> 1;     if (q < So) o[no++] = q;
    }
}

// ---------- stage kernels ----------
__global__ __launch_bounds__(256) void k_init(const float* __restrict__ vf,
                                              const int* __restrict__ coors,
                                              float* __restrict__ x,
                                              int* __restrict__ lut0,
                                              int* __restrict__ om1) {
    int i = blockIdx.x * 256 + threadIdx.x;
    if (i >= NN) return;
    x[i] = log10f(vf[i * 2]);
    int c1 = coors[i * 4 + 1], c2 = coors[i * 4 + 2], c3 = coors[i * 4 + 3];
    int e = 2 * c1 - 9, rg = 2 * c2, az = 2 * c3 + 149;
    atomicMax(&lut0[(e * S0_1 + rg) * S0_2 + az], i);
    int A[2], B[2], C[2]; int na, nb, nc;
    cand(e, S1_0, A, na); cand(rg, S1_1, B, nb); cand(az, S1_2, C, nc);
    for (int ia = 0; ia < na; ia++)
        for (int ib = 0; ib < nb; ib++)
            for (int ic = 0; ic < nc; ic++)
                om1[(A[ia] * S1_1 + B[ib]) * S1_2 + C[ic]] = 1;
}

// ---------- MFMA attention ----------
#define QS 40
__global__ __launch_bounds__(256, 1) void k_attn(float* __restrict__ x_io,
    const int* __restrict__ coors,
    const float* __restrict__ et, const float* __restrict__ at,
    const float* __restrict__ wq, const float* __restrict__ bq,
    const float* __restrict__ wk, const float* __restrict__ bk,
    const float* __restrict__ wv, const float* __restrict__ bv) {
    __shared__ float xin[KK * 7];
    __shared__ unsigned short ksh_h[256 * QS];
    __shared__ unsigned short ksh_l[256 * QS];
    __shared__ float vsh[256];
    const int r = blockIdx.x;
    const int t = threadIdx.x;
    const int w = t >> 6, ln = t & 63, l31 = ln & 31, lh = ln >> 5;

    for (int i = t; i < KK; i += 256) {
        int gi = r * KK + i;
        xin[i * 7 + 0] = x_io[gi];
        int c1 = coors[gi * 4 + 1], c3 = coors[gi * 4 + 3];
        xin[i * 7 + 1] = et[c1 * 3 + 0]; xin[i * 7 + 2] = et[c1 * 3 + 1]; xin[i * 7 + 3] = et[c1 * 3 + 2];
        xin[i * 7 + 4] = at[c3 * 3 + 0]; xin[i * 7 + 5] = at[c3 * 3 + 1]; xin[i * 7 + 6] = at[c3 * 3 + 2];
    }
    __syncthreads();

    union U8 { bf16x8 v; unsigned short u[8]; };

    for (int l = 0; l < 4; l++) {
        const float* wql = wq + l * 7 * 32; const float* bql = bq + l * 32;
        const float* wkl = wk + l * 7 * 32; const float* bkl = bk + l * 32;
        const float* wvl = wv + l * 7;      const float  bvl = bv[l];
        float qh_f[32], ql_f[32];
        if (t < KK) {
            float xi[7];
            #pragma unroll
            for (int ci = 0; ci < 7; ci++) xi[ci] = xin[t * 7 + ci];
            float av = bvl;
            #pragma unroll
            for (int ci = 0; ci < 7; ci++) av += xi[ci] * wvl[ci];
            vsh[t] = av;
            #pragma unroll
            for (int d = 0; d < 32; d++) {
                float aq = bql[d], ak = bkl[d];
                #pragma unroll
                for (int ci = 0; ci < 7; ci++) { aq += xi[ci] * wql[ci * 32 + d]; ak += xi[ci] * wkl[ci * 32 + d]; }
                aq *= ATT_SCALE;
                float h = b2f(f2b(aq));
                qh_f[d] = h; ql_f[d] = aq - h;
                unsigned short k16 = f2b(ak);
                ksh_h[t * QS + d] = k16;
                ksh_l[t * QS + d] = f2b(ak - b2f(k16));
            }
        } else {
            #pragma unroll
            for (int d = 0; d < 32; d++) {
                qh_f[d] = 0.f; ql_f[d] = 0.f;
                ksh_h[t * QS + d] = 0; ksh_l[t * QS + d] = 0;
            }
            vsh[t] = 0.f;
        }
        __syncthreads();

        U8 Bh[2][2], Bl[2][2];
        #pragma unroll
        for (int b = 0; b < 2; b++) {
            int src = b * 32 + l31;
            #pragma unroll
            for (int ks = 0; ks < 2; ks++) {
                #pragma unroll
                for (int j = 0; j < 8; j++) {
                    float h0 = __shfl(qh_f[ks * 16 + j],     src, 64);
                    float h1 = __shfl(qh_f[ks * 16 + 8 + j], src, 64);
                    float l0 = __shfl(ql_f[ks * 16 + j],     src, 64);
                    float l1 = __shfl(ql_f[ks * 16 + 8 + j], src, 64);
                    Bh[b][ks].u[j] = f2b(lh ? h1 : h0);
                    Bl[b][ks].u[j] = f2b(lh ? l1 : l0);
                }
            }
        }

        float m[2]  = {-1e30f, -1e30f};
        float den[2] = {0.f, 0.f};
        float num[2] = {0.f, 0.f};

        for (int mt = 0; mt < 8; mt++) {
            U8 Ah[2], Al[2];
            int krow = mt * 32 + l31;
            #pragma unroll
            for (int ks = 0; ks < 2; ks++) {
                Ah[ks].v = *(const bf16x8*)&ksh_h[krow * QS + ks * 16 + lh * 8];
                Al[ks].v = *(const bf16x8*)&ksh_l[krow * QS + ks * 16 + lh * 8];
            }
            float4 v4[4];
            #pragma unroll
            for (int c = 0; c < 4; c++)
                v4[c] = *(const float4*)&vsh[mt * 32 + 8 * c + 4 * lh];

            #pragma unroll
            for (int b = 0; b < 2; b++) {
                f32x16 acc;
                #pragma unroll
                for (int q = 0; q < 16; q++) acc[q] = 0.f;
                acc = __builtin_amdgcn_mfma_f32_32x32x16_bf16(Ah[0].v, Bh[b][0].v, acc, 0, 0, 0);
                acc = __builtin_amdgcn_mfma_f32_32x32x16_bf16(Ah[1].v, Bh[b][1].v, acc, 0, 0, 0);
                acc = __builtin_amdgcn_mfma_f32_32x32x16_bf16(Ah[0].v, Bl[b][0].v, acc, 0, 0, 0);
                acc = __builtin_amdgcn_mfma_f32_32x32x16_bf16(Ah[1].v, Bl[b][1].v, acc, 0, 0, 0);
                acc = __builtin_amdgcn_mfma_f32_32x32x16_bf16(Al[0].v, Bh[b][0].v, acc, 0, 0, 0);
                acc = __builtin_amdgcn_mfma_f32_32x32x16_bf16(Al[1].v, Bh[b][1].v, acc, 0, 0, 0);

                float s[16];
                #pragma unroll
                for (int rr = 0; rr < 16; rr++) {
                    s[rr] = acc[rr];
                    if (mt == 7) {
                        int key = 224 + (rr & 3) + 8 * (rr >> 2) + 4 * lh;
                        if (key >= KK) s[rr] = -1e30f;
                    }
                }
                float cm = s[0];
                #pragma unroll
                for (int rr = 1; rr < 16; rr++) cm = fmaxf(cm, s[rr]);
                cm = fmaxf(cm, __shfl_xor(cm, 32, 64));
                float mn = fmaxf(m[b], cm);
                float alpha = __expf(m[b] - mn);
                float dsum = 0.f, nsum = 0.f;
                #pragma unroll
                for (int rr = 0; rr < 16; rr++) {
                    float e = __expf(s[rr] - mn);
                    dsum += e;
                    nsum += e * ((&v4[rr >> 2].x)[rr & 3]);
                }
                den[b] = den[b] * alpha + dsum;
                num[b] = num[b] * alpha + nsum;
                m[b] = mn;
            }
        }
        __syncthreads();
        #pragma unroll
        for (int b = 0; b < 2; b++) {
            float dtot = den[b] + __shfl_xor(den[b], 32, 64);
            float ntot = num[b] + __shfl_xor(num[b], 32, 64);
            int q = (w * 2 + b) * 32 + l31;
            if (lh == 0 && q < KK) xin[q * 7] = ntot / dtot;
        }
        __syncthreads();
    }
    for (int i = t; i < KK; i += 256) x_io[r * KK + i] = xin[i * 7];
}

__global__ __launch_bounds__(256) void k_f0(const int* __restrict__ coors,
    const float* __restrict__ x,
    const float* __restrict__ w_in, const float* __restrict__ b_in,
    const float* __restrict__ gg, const float* __restrict__ gb,
    unsigned short* __restrict__ f0) {
    int i = blockIdx.x * 256 + threadIdx.x;
    if (i >= NN) return;
    int c1 = coors[i * 4 + 1], c2 = coors[i * 4 + 2], c3 = coors[i * 4 + 3];
    float fe0 = (float)(2 * c1 - 9), fe1 = (float)(2 * c2), fe2 = (float)(2 * c3 + 149), fe3 = x[i];
    float tv[16];
    #pragma unroll
    for (int c = 0; c < 16; c++)
        tv[c] = b_in[c] + fe0 * w_in[c] + fe1 * w_in[16 + c] + fe2 * w_in[32 + c] + fe3 * w_in[48 + c];
    #pragma unroll
    for (int g = 0; g < 8; g++) {
        float a = tv[2 * g], b = tv[2 * g + 1];
        float m = 0.5f * (a + b);
        float va = 0.5f * ((a - m) * (a - m) + (b - m) * (b - m));
        float inv = rsqrtf(va + 1e-5f);
        f0[i * 16 + 2 * g]     = f2b(fmaxf((a - m) * inv * gg[2 * g]     + gb[2 * g],     0.f));
        f0[i * 16 + 2 * g + 1] = f2b(fmaxf((b - m) * inv * gg[2 * g + 1] + gb[2 * g + 1], 0.f));
    }
}

__global__ __launch_bounds__(256) void k_blocksum(const int* __restrict__ om,
                                                  int* __restrict__ partials, int ncells) {
    __shared__ int sh[256];
    int t = threadIdx.x;
    int base = blockIdx.x * 1024 + t * 4;
    int s = 0;
    #pragma unroll
    for (int q = 0; q < 4; q++) s += (base + q < ncells) ? om[base + q] : 0;
    int incl = block_incl_scan(s, sh);
    if (t == 255) partials[blockIdx.x] = incl;
}

__global__ __launch_bounds__(256) void k_scanparts(int* __restrict__ partials, int nparts,
                                                   int* __restrict__ pcnt, int cap) {
    __shared__ int sh[256];
    __shared__ int tot;
    int t = threadIdx.x;
    int chunk = (nparts + 255) / 256;
    int beg = t * chunk;
    int vals[8];
    int s = 0;
    #pragma unroll
    for (int i = 0; i < 8; i++) {
        if (i < chunk) {
            int ix = beg + i;
            int x = (ix < nparts) ? partials[ix] : 0;
            vals[i] = x; s += x;
        }
    }
    int incl = block_incl_scan(s, sh);
    int excl = incl - s;
    if (t == 255) tot = incl;
    int run = excl;
    #pragma unroll
    for (int i = 0; i < 8; i++) {
        if (i < chunk) {
            int ix = beg + i;
            if (ix < nparts) { partials[ix] = run; run += vals[i]; }
        }
    }
    __syncthreads();
    if (t == 0) *pcnt = min(tot, cap);
}

__global__ __launch_bounds__(256) void k_emit(const int* __restrict__ om,
                                              const int* __restrict__ partials,
                                              int* __restrict__ oc,
                                              int ncells, int D1, int D2, int cap) {
    __shared__ int sh[256];
    int t = threadIdx.x;
    int base = blockIdx.x * 1024 + t * 4;
    int v[4]; int s = 0;
    #pragma unroll
    for (int q = 0; q < 4; q++) { v[q] = (base + q < ncells) ? om[base + q] : 0; s += v[q]; }
    int incl = block_incl_scan(s, sh);
    int run = partials[blockIdx.x] + (incl - s);
    int D12 = D1 * D2;
    #pragma unroll
    for (int q = 0; q < 4; q++) {
        if (v[q]) {
            if (run < cap) {
                int lin = base + q;
                int i0 = lin / D12;
                int r2 = lin - i0 * D12;
                int i1 = r2 / D2;
                int i2 = r2 - i1 * D2;
                oc[run * 3] = i0; oc[run * 3 + 1] = i1; oc[run * 3 + 2] = i2;
            }
            run++;
        }
    }
}

__global__ __launch_bounds__(256) void k_lutscatter(const int* __restrict__ oc,
                                                    const int* __restrict__ pc,
                                                    int* __restrict__ lut, int D1, int D2) {
    int j = blockIdx.x * 256 + threadIdx.x;
    if (j >= *pc) return;
    lut[(oc[j * 3] * D1 + oc[j * 3 + 1]) * D2 + oc[j * 3 + 2]] = j;
}

__global__ __launch_bounds__(256) void k_lutscatter2(const int* __restrict__ oc,
                                                     const int* __restrict__ pc,
                                                     int* __restrict__ lut,
                                                     int* __restrict__ lut_t) {
    int j = blockIdx.x * 256 + threadIdx.x;
    if (j >= *pc) return;
    int a = oc[j * 3], b = oc[j * 3 + 1], c = oc[j * 3 + 2];
    lut[(a * S2_1 + b) * S2_2 + c] = j;
    lut_t[(c * S2_1 + b) * S2_0 + a] = j;
}

__global__ __launch_bounds__(256) void k_mask2(const int* __restrict__ oc,
                                               const int* __restrict__ pc,
                                               int* __restrict__ om) {
    int j = blockIdx.x * 256 + threadIdx.x;
    if (j >= *pc) return;
    int p0 = oc[j * 3], p1 = oc[j * 3 + 1], p2 = oc[j * 3 + 2];
    int A[2], B[2], C[2]; int na, nb, nc;
    cand(p0, S2_0, A, na); cand(p1, S2_1, B, nb); cand(p2, S2_2, C, nc);
    for (int ia = 0; ia < na; ia++)
        for (int ib = 0; ib < nb; ib++)
            for (int ic = 0; ic < nc; ic++)
                om[(A[ia] * S2_1 + B[ib]) * S2_2 + C[ic]] = 1;
}

// ---------- weight pre-pack into MFMA B-fragment order ----------
__global__ __launch_bounds__(256) void k_prepack(const float* __restrict__ w,
        unsigned short* __restrict__ wp, int nk, int cin, int cout) {
    int tid = blockIdx.x * 256 + threadIdx.x;
    int tot = nk * cin * cout;
    if (tid >= tot) return;
    int co = tid % cout; int rest = tid / cout; int ci = rest % cin; int kk = rest / cin;
    int ks = ci >> 4, kr = ci & 15, half = kr >> 3, j = kr & 7;
    int nt = co >> 5, cl = co & 31, lane = half * 32 + cl;
    wp[((((size_t)kk * (cin >> 4) + ks) * (cout >> 5) + nt) * 64 + lane) * 8 + j] = f2b(w[tid]);
}

// ---------- neighbor-index table (level 2) ----------
template<bool DOWN, int SD0, int SD1, int SD2>
__global__ __launch_bounds__(256) void k_nbidx(const int* __restrict__ oc,
        const int* __restrict__ pc, const int* __restrict__ lut,
        int* __restrict__ nb, int NBx, int ZR) {
    int gid = blockIdx.x * 256 + threadIdx.x;
    if (gid >= 27 * NBx) return;
    int k = gid / NBx, j = gid - k * NBx;
    int idx = ZR;
    if (j < *pc) {
        int dx = k / 9 - 1, dy = (k / 3) % 3 - 1, dz = k % 3 - 1;
        int x = oc[j * 3], y = oc[j * 3 + 1], z = oc[j * 3 + 2];
        if (DOWN) { x = 2 * x + dx; y = 2 * y + dy; z = 2 * z + dz; }
        else      { x += dx; y += dy; z += dz; }
        if ((unsigned)x < (unsigned)SD0 && (unsigned)y < (unsigned)SD1 && (unsigned)z < (unsigned)SD2) {
            int v = lut[(x * SD1 + y) * SD2 + z];
            if (v >= 0) idx = v;
        }
    }
    nb[gid] = idx;
}

// ---------- async DMA MFMA gather-conv ----------
// 128 rows x COUT per block, 256 threads = 4 waves.
// A staged via __builtin_amdgcn_global_load_lds (16B/lane, double-buffered
// LDS, zero data VGPRs). Wave w stages rows w*32..+31 (IPW DMA instrs).
// One __syncthreads per K-step: the compiler's vmcnt(0)-before-barrier
// drains DMAs issued one full MFMA section earlier.
// No-padding LDS forced by DMA (lane-linear) -> XOR swizzle: chunk c of
// row r lives at slot c ^ ((r>>SH)&(CPR-1)) (applied on the global address
// at stage time, mirrored at ds_read time) -> 4 lanes/bank-quad.
// COUT=128: wave owns cols w*32..+31, all 128 rows (TM=4).
// COUT=32:  wave owns rows w*32..+31 (TM=1), all 32 cols.
// MODE 0: bn+relu  MODE 1: bn+res+relu  MODE 2: bias+gn16+relu -> fo_t
template<int CIN, int COUT, int SD0, int SD1, int SD2, bool DOWN, int MODE, bool TAB>
__global__ __launch_bounds__(256, 2)
void k_aconv(const unsigned short* __restrict__ fin, const int* __restrict__ lut,
             const int* __restrict__ nb, int NBx,
             const int* __restrict__ oc, const int* __restrict__ pc,
             const unsigned short* __restrict__ wp,
             const float* __restrict__ p0, const float* __restrict__ p1,
             const float* __restrict__ p2,
             const unsigned short* __restrict__ res, void* __restrict__ fout_,
             int ZR) {
    constexpr int KS  = CIN / 16;
    constexpr int NTT = COUT / 32;
    constexpr int TM  = (COUT == 128) ? 4 : 1;
    constexpr int CPR = CIN / 8;             // 16B chunks per row
    constexpr int RPI = 64 / CPR;            // rows per DMA instruction
    constexpr int IPW = 32 / RPI;            // DMA instructions per wave
    constexpr int SH  = (CPR == 16) ? 0 : ((CPR == 4) ? 1 : 2);
    __shared__ unsigned short sA[2 * 128 * CIN];

    const int n = *pc;
    const int blk = xcd_swizzle(blockIdx.x, gridDim.x);
    const int j0 = blk * 128;
    if (j0 >= n) return;
    const int t = threadIdx.x;
    const int w = t >> 6, ln = t & 63, l31 = ln & 31, lh = ln >> 5;
    const int rowb = (COUT == 128) ? 0 : w * 32;
    const int colt = (COUT == 128) ? w : 0;

    // this lane's staging rows (one per DMA instruction)
    const int lrow = ln / CPR;               // row within instruction group
    const int slot = ln % CPR;
    int myrow[IPW];
    #pragma unroll
    for (int i = 0; i < IPW; i++) myrow[i] = w * 32 + i * RPI + lrow;

    // inline-lut coords (level-1)
    int cxa[IPW], cya[IPW], cza[IPW];
    if (!TAB) {
        #pragma unroll
        for (int i = 0; i < IPW; i++) {
            int j = j0 + myrow[i];
            if (j < n) { cxa[i] = oc[j * 3]; cya[i] = oc[j * 3 + 1]; cza[i] = oc[j * 3 + 2]; }
            else       { cxa[i] = -1000000; cya[i] = -1000000; cza[i] = -1000000; }
        }
    }

    auto fetchIdx = [&](int kk, int* ir) {
        if (TAB) {
            #pragma unroll
            for (int i = 0; i < IPW; i++)
                ir[i] = nb[kk * NBx + j0 + myrow[i]];
        } else {
            int dx = kk / 9 - 1, dy = (kk / 3) % 3 - 1, dz = kk % 3 - 1;
            #pragma unroll
            for (int i = 0; i < IPW; i++) {
                int x, y, z;
                if (DOWN) { x = 2 * cxa[i] + dx; y = 2 * cya[i] + dy; z = 2 * cza[i] + dz; }
                else      { x = cxa[i] + dx; y = cya[i] + dy; z = cza[i] + dz; }
                int idx = -1;
                if ((unsigned)x < (unsigned)SD0 && (unsigned)y < (unsigned)SD1 && (unsigned)z < (unsigned)SD2)
                    idx = lut[(x * SD1 + y) * SD2 + z];
                ir[i] = idx < 0 ? ZR : idx;
            }
        }
    };

    // issue DMA stage of the rows for one k-step into buffer buf
    auto stage = [&](int buf, const int* ir) {
        #pragma unroll
        for (int i = 0; i < IPW; i++) {
            unsigned short* ldsb = &sA[(size_t)buf * 128 * CIN + (w * 32 + i * RPI) * CIN]; // wave-uniform
            int g = (myrow[i] >> SH) & (CPR - 1);
            const unsigned short* gp = fin + (size_t)ir[i] * CIN + ((slot ^ g) * 8);
            gld_lds16(ldsb, gp);
        }
    };

    f32x16 acc[TM];
    #pragma unroll
    for (int a = 0; a < TM; a++)
        #pragma unroll
        for (int q = 0; q < 16; q++) acc[a][q] = 0.f;

    int irn[IPW];
    fetchIdx(0, irn);
    stage(0, irn);
    fetchIdx(1, irn);

    for (int k = 0; k < 27; k++) {
        __syncthreads();                     // vmcnt(0) drain precedes barrier
        if (k < 26) {
            stage((k + 1) & 1, irn);         // DMA for k+1 (in flight over MFMAs)
            fetchIdx(k + 2 <= 26 ? k + 2 : 26, irn);
        }
        const unsigned short* wk = wp + (size_t)k * KS * NTT * 512;
        const unsigned short* bufA = &sA[(size_t)(k & 1) * 128 * CIN];
        #pragma unroll
        for (int ks = 0; ks < KS; ks++) {
            bf16x8 bfr = *(const bf16x8*)(wk + ((size_t)(ks * NTT + colt) * 64 + ln) * 8);
            #pragma unroll
            for (int a = 0; a < TM; a++) {
                int r = rowb + a * 32 + l31;
                int c = ks * 2 + lh;
                int sl = c ^ ((r >> SH) & (CPR - 1));
                bf16x8 afr = *(const bf16x8*)(bufA + (size_t)r * CIN + sl * 8);
                acc[a] = __builtin_amdgcn_mfma_f32_32x32x16_bf16(afr, bfr, acc[a], 0, 0, 0);
            }
        }
    }

    const int co = colt * 32 + l31;
    if (MODE != 2) {
        unsigned short* fout = (unsigned short*)fout_;
        float g_ = p0[co], bb_ = p0[COUT + co], m_ = p0[2 * COUT + co];
        float iv = rsqrtf(p0[3 * COUT + co] + 1e-3f);
        #pragma unroll
        for (int a = 0; a < TM; a++) {
            #pragma unroll
            for (int r = 0; r < 16; r++) {
                int j = j0 + rowb + a * 32 + (r & 3) + 8 * (r >> 2) + 4 * lh;
                if (j < n) {
                    float y = (acc[a][r] - m_) * iv * g_ + bb_;
                    if (MODE == 1) y += b2f(res[(size_t)j * COUT + co]);
                    fout[(size_t)j * COUT + co] = f2b(fmaxf(y, 0.f));
                }
            }
        }
    } else {
        float* fo_t = (float*)fout_;
        float bias = p0[co], gg_ = p1[co], gb_ = p2[co];
        #pragma unroll
        for (int a = 0; a < TM; a++) {
            #pragma unroll
            for (int r = 0; r < 16; r++) {
                int j = j0 + rowb + a * 32 + (r & 3) + 8 * (r >> 2) + 4 * lh;
                float y = acc[a][r] + bias;
                float s = y;
                s += __shfl_xor(s, 1, 8);
                s += __shfl_xor(s, 2, 8);
                s += __shfl_xor(s, 4, 8);
                float m = s * 0.125f;
                float d = y - m;
                float q2 = d * d;
                q2 += __shfl_xor(q2, 1, 8);
                q2 += __shfl_xor(q2, 2, 8);
                q2 += __shfl_xor(q2, 4, 8);
                float var = q2 * 0.125f;
                float o = fmaxf(d * rsqrtf(var + 1e-5f) * gg_ + gb_, 0.f);
                fo_t[(size_t)co * FOP + j] = o;
            }
        }
    }
}

// ---------- dense output scatter (coalesced reads AND writes) ----------
__global__ __launch_bounds__(256) void k_scatter(const float* __restrict__ fo_t,
                                                 const int* __restrict__ lut2t,
                                                 float* __restrict__ dout) {
    int gid = blockIdx.x * 256 + threadIdx.x;
    int cell = gid % CELLS2;
    int co = gid / CELLS2;
    int idx = lut2t[cell];
    float v = 0.f;
    if (idx >= 0) v = fo_t[(size_t)co * FOP + idx];
    dout[gid] = v;
}

// ---------- host ----------
extern "C" void kernel_launch(void* const* d_in, const int* in_sizes, int n_in,
                              void* d_out, int out_size, void* d_ws, size_t ws_size,
                              hipStream_t stream) {
    const float* vf    = (const float*)d_in[0];
    const int*   coors = (const int*)d_in[1];
    const float* et    = (const float*)d_in[3];
    const float* at    = (const float*)d_in[4];
    const float* wq    = (const float*)d_in[5];
    const float* bq    = (const float*)d_in[6];
    const float* wk_   = (const float*)d_in[7];
    const float* bk    = (const float*)d_in[8];
    const float* wv    = (const float*)d_in[9];
    const float* bv    = (const float*)d_in[10];
    const float* w_in  = (const float*)d_in[11];
    const float* b_in  = (const float*)d_in[12];
    const float* gin_g = (const float*)d_in[13];
    const float* gin_b = (const float*)d_in[14];
    const float* w_d1  = (const float*)d_in[15];
    const float* bn_d1 = (const float*)d_in[16];
    const float* w_r1  = (const float*)d_in[17];
    const float* bn_r1 = (const float*)d_in[18];
    const float* w_d2  = (const float*)d_in[19];
    const float* bn_d2 = (const float*)d_in[20];
    const float* w_r2  = (const float*)d_in[21];
    const float* bn_r2 = (const float*)d_in[22];
    const float* w_out = (const float*)d_in[23];
    const float* b_out = (const float*)d_in[24];
    const float* gout_g= (const float*)d_in[25];
    const float* gout_b= (const float*)d_in[26];

    char* ws = (char*)d_ws;
    size_t cur = 0;
    auto take = [&](size_t bytes) -> char* {
        char* p = ws + cur;
        cur += (bytes + 255) & ~(size_t)255;
        return p;
    };
    size_t usz1 = (size_t)4194304 + (size_t)CELLS0 * 4;
    size_t usz2 = (size_t)17694720 + (size_t)128 * FOP * 4;
    char* U = take(usz1 > usz2 ? usz1 : usz2);
    float*          x_att = (float*)U;
    unsigned short* f0    = (unsigned short*)(U + 262144);
    int*            lut0  = (int*)(U + 4194304);
    unsigned short* fB1   = (unsigned short*)U;
    unsigned short* fA2   = (unsigned short*)U;
    unsigned short* fB2   = (unsigned short*)(U + 17694720);
    float*          fo_t  = (float*)(U + 17694720);

    int*   om1      = (int*)take((size_t)CELLS1 * 4);
    int*   om2      = (int*)take((size_t)CELLS2 * 4);
    int*   partials = (int*)take(8192);
    int*   cnt      = (int*)take(256);
    int*   oc1      = (int*)take((size_t)CAP1 * 3 * 4);
    int*   oc2      = (int*)take((size_t)CAP2 * 3 * 4);
    unsigned short* fA1 = (unsigned short*)take((size_t)(CAP1 + 1) * C1 * 2);
    int*   lut1     = (int*)take((size_t)CELLS1 * 4);
    int*   lut2     = (int*)take((size_t)CELLS2 * 4);
    int*   lut2t    = (int*)take((size_t)CELLS2 * 4);
    int*   nb_d2    = (int*)take((size_t)27 * NB2X * 4);
    int*   nb_r2    = (int*)take((size_t)27 * NB2X * 4);
    unsigned short* wp_d1  = (unsigned short*)take((size_t)27 * 16 * 32 * 2);
    unsigned short* wp_r1  = (unsigned short*)take((size_t)108 * 32 * 32 * 2);
    unsigned short* wp_d2  = (unsigned short*)take((size_t)27 * 32 * 128 * 2);
    unsigned short* wp_r2  = (unsigned short*)take((size_t)108 * 128 * 128 * 2);
    unsigned short* wp_out = (unsigned short*)take((size_t)27 * 128 * 128 * 2);

    hipMemsetAsync(lut0, 0xFF, (size_t)CELLS0 * 4, stream);
    hipMemsetAsync(om1, 0, (size_t)CELLS1 * 4, stream);
    hipMemsetAsync(om2, 0, (size_t)CELLS2 * 4, stream);
    hipMemsetAsync(lut1, 0xFF, (size_t)CELLS1 * 4, stream);
    hipMemsetAsync(lut2, 0xFF, (size_t)CELLS2 * 4, stream);
    hipMemsetAsync(lut2t, 0xFF, (size_t)CELLS2 * 4, stream);
    hipMemsetAsync(f0 + (size_t)NN * 16, 0, 32, stream);        // f0 zero row (ZR=NN)
    hipMemsetAsync(fA1 + (size_t)CAP1 * C1, 0, 64, stream);     // fA1 zero row (ZR=CAP1)

    const int gN  = (NN + 255) / 256;
    const int gB1 = CELLS1 / 1024;
    const int gB2 = CELLS2 / 1024;
    const int gM1 = (CAP1 + 127) / 128;   // 2735
    const int gM2 = (CAP2 + 127) / 128;   // 540
    const int gS1 = (CAP1 + 255) / 256;
    const int gS2 = (CAP2 + 255) / 256;
    const int gNB = (27 * NB2X + 255) / 256;

    k_prepack<<<(27*16*32   + 255)/256, 256, 0, stream>>>(w_d1,  wp_d1, 27, 16, 32);
    k_prepack<<<(108*32*32  + 255)/256, 256, 0, stream>>>(w_r1,  wp_r1, 108, 32, 32);
    k_prepack<<<(27*32*128  + 255)/256, 256, 0, stream>>>(w_d2,  wp_d2, 27, 32, 128);
    k_prepack<<<(108*128*128+ 255)/256, 256, 0, stream>>>(w_r2,  wp_r2, 108, 128, 128);
    k_prepack<<<(27*128*128 + 255)/256, 256, 0, stream>>>(w_out, wp_out, 27, 128, 128);

    k_init<<<gN, 256, 0, stream>>>(vf, coors, x_att, lut0, om1);
    k_attn<<<NRR, 256, 0, stream>>>(x_att, coors, et, at, wq, bq, wk_, bk, wv, bv);
    k_f0<<<gN, 256, 0, stream>>>(coors, x_att, w_in, b_in, gin_g, gin_b, f0);

    k_blocksum<<<gB1, 256, 0, stream>>>(om1, partials, CELLS1);
    k_scanparts<<<1, 256, 0, stream>>>(partials, gB1, cnt, CAP1);
    k_emit<<<gB1, 256, 0, stream>>>(om1, partials, oc1, CELLS1, S1_1, S1_2, CAP1);

    // down conv 1 (16 -> 32), inline lut0
    k_aconv<16, 32, S0_0, S0_1, S0_2, true, 0, false><<<gM1, 256, 0, stream>>>(
        f0, lut0, nullptr, 0, oc1, cnt, wp_d1, bn_d1, nullptr, nullptr, nullptr, fA1, NN);
    k_lutscatter<<<gS1, 256, 0, stream>>>(oc1, cnt, lut1, S1_1, S1_2);
    hipMemsetAsync(fB1 + (size_t)CAP1 * C1, 0, 64, stream);     // fB1 zero row

    // resblocks level 1 (32 ch), inline lut1
    k_aconv<32, 32, S1_0, S1_1, S1_2, false, 0, false><<<gM1, 256, 0, stream>>>(
        fA1, lut1, nullptr, 0, oc1, cnt, wp_r1 + 0 * 27648, bn_r1 + 0 * 128, nullptr, nullptr, nullptr, fB1, CAP1);
    k_aconv<32, 32, S1_0, S1_1, S1_2, false, 1, false><<<gM1, 256, 0, stream>>>(
        fB1, lut1, nullptr, 0, oc1, cnt, wp_r1 + 1 * 27648, bn_r1 + 1 * 128, nullptr, nullptr, fA1, fA1, CAP1);
    k_aconv<32, 32, S1_0, S1_1, S1_2, false, 0, false><<<gM1, 256, 0, stream>>>(
        fA1, lut1, nullptr, 0, oc1, cnt, wp_r1 + 2 * 27648, bn_r1 + 2 * 128, nullptr, nullptr, nullptr, fB1, CAP1);
    k_aconv<32, 32, S1_0, S1_1, S1_2, false, 1, false><<<gM1, 256, 0, stream>>>(
        fB1, lut1, nullptr, 0, oc1, cnt, wp_r1 + 3 * 27648, bn_r1 + 3 * 128, nullptr, nullptr, fA1, fA1, CAP1);

    k_mask2<<<gS1, 256, 0, stream>>>(oc1, cnt, om2);
    k_blocksum<<<gB2, 256, 0, stream>>>(om2, partials, CELLS2);
    k_scanparts<<<1, 256, 0, stream>>>(partials, gB2, cnt + 1, CAP2);
    k_emit<<<gB2, 256, 0, stream>>>(om2, partials, oc2, CELLS2, S2_1, S2_2, CAP2);

    // level-2 neighbor tables + zero rows
    k_nbidx<true, S1_0, S1_1, S1_2><<<gNB, 256, 0, stream>>>(oc2, cnt + 1, lut1, nb_d2, NB2X, CAP1);
    hipMemsetAsync(fA2 + (size_t)CAP2 * C2, 0, 256, stream);
    hipMemsetAsync(fB2 + (size_t)CAP2 * C2, 0, 256, stream);

    // down conv 2 (32 -> 128), nb table
    k_aconv<32, 128, S1_0, S1_1, S1_2, true, 0, true><<<gM2, 256, 0, stream>>>(
        fA1, nullptr, nb_d2, NB2X, oc2, cnt + 1, wp_d2, bn_d2, nullptr, nullptr, nullptr, fA2, CAP1);
    k_lutscatter2<<<gS2, 256, 0, stream>>>(oc2, cnt + 1, lut2, lut2t);
    k_nbidx<false, S2_0, S2_1, S2_2><<<gNB, 256, 0, stream>>>(oc2, cnt + 1, lut2, nb_r2, NB2X, CAP2);

    const size_t wr2s = (size_t)27 * 128 * 128;
    k_aconv<128, 128, S2_0, S2_1, S2_2, false, 0, true><<<gM2, 256, 0, stream>>>(
        fA2, nullptr, nb_r2, NB2X, oc2, cnt + 1, wp_r2 + 0 * wr2s, bn_r2 + 0 * 512, nullptr, nullptr, nullptr, fB2, CAP2);
    k_aconv<128, 128, S2_0, S2_1, S2_2, false, 1, true><<<gM2, 256, 0, stream>>>(
        fB2, nullptr, nb_r2, NB2X, oc2, cnt + 1, wp_r2 + 1 * wr2s, bn_r2 + 1 * 512, nullptr, nullptr, fA2, fA2, CAP2);
    k_aconv<128, 128, S2_0, S2_1, S2_2, false, 0, true><<<gM2, 256, 0, stream>>>(
        fA2, nullptr, nb_r2, NB2X, oc2, cnt + 1, wp_r2 + 2 * wr2s, bn_r2 + 2 * 512, nullptr, nullptr, nullptr, fB2, CAP2);
    k_aconv<128, 128, S2_0, S2_1, S2_2, false, 1, true><<<gM2, 256, 0, stream>>>(
        fB2, nullptr, nb_r2, NB2X, oc2, cnt + 1, wp_r2 + 3 * wr2s, bn_r2 + 3 * 512, nullptr, nullptr, fA2, fA2, CAP2);

    k_aconv<128, 128, S2_0, S2_1, S2_2, false, 2, true><<<gM2, 256, 0, stream>>>(
        fA2, nullptr, nb_r2, NB2X, oc2, cnt + 1, wp_out, b_out, gout_g, gout_b, nullptr, fo_t, CAP2);
    k_scatter<<<(S2_0 * S2_1 * S2_2 * 128) / 256, 256, 0, stream>>>(fo_t, lut2t, (float*)d_out);
}

// Round 9
// 1210.017 us; speedup vs baseline: 1.6239x; 1.0987x over previous
//
#include <hip/hip_runtime.h>
#include <math.h>

#define NRR 175
#define KK 250
#define NN (NRR*KK)

#define S0_0 56
#define S0_1 350
#define S0_2 512
#define S1_0 28
#define S1_1 175
#define S1_2 256
#define S2_0 14
#define S2_1 88
#define S2_2 128
#define CAP1 350000
#define CAP2 69000
#define C1 32
#define C2 128
#define FOP 69632   // fo_t row stride (padded)
#define NB2X 69120  // 540*128, level-2 nb table stride

#define CELLS0 (S0_0*S0_1*S0_2)   // 10035200
#define CELLS1 (S1_0*S1_1*S1_2)   // 1254400
#define CELLS2 (S2_0*S2_1*S2_2)   // 157696

#define ATT_SCALE 0.17677669529663687f

typedef __attribute__((ext_vector_type(8))) __bf16 bf16x8;
typedef __attribute__((ext_vector_type(16))) float f32x16;

typedef __attribute__((address_space(3))) unsigned int       lds_u32;
typedef const __attribute__((address_space(1))) unsigned int glb_u32;

// async global->LDS, 16B per lane, LDS dest = wave-uniform base + lane*16
__device__ __forceinline__ void gld_lds16(unsigned short* lds_base, const unsigned short* gptr) {
    __builtin_amdgcn_global_load_lds((glb_u32*)gptr, (lds_u32*)lds_base, 16, 0, 0);
}

// ---------- bf16 helpers (RNE) ----------
__device__ __forceinline__ unsigned short f2b(float x) {
    unsigned int u = __builtin_bit_cast(unsigned int, x);
    unsigned int r = u + 0x7FFFu + ((u >> 16) & 1u);
    return (unsigned short)(r >> 16);
}
__device__ __forceinline__ float b2f(unsigned short h) {
    return __builtin_bit_cast(float, (unsigned int)h << 16);
}

// XCD-contiguous block swizzle
__device__ __forceinline__ int xcd_swizzle(int b, int nx) {
    int per = nx >> 3, rem = nx & 7;
    int x = b & 7, i = b >> 3;
    return x * per + min(x, rem) + i;
}

// ---------- helpers ----------
__device__ __forceinline__ int block_incl_scan(int v, int* s) {
    int t = threadIdx.x;
    s[t] = v; __syncthreads();
    #pragma unroll
    for (int d = 1; d < 256; d <<= 1) {
        int x = (t >= d) ? s[t - d] : 0;
        __syncthreads();
        s[t] += x;
        __syncthreads();
    }
    return s[t];
}

__device__ __forceinline__ void cand(int p, int So, int* o, int& no) {
    no = 0;
    if ((p & 1) == 0) {
        int q = p >> 1; if (q < So) o[no++] = q;
    } else {
        int q = (p - 1) >> 1; if (q < So) o[no++] = q;
        q = (p + 1) >> 1;     if (q < So) o[no++] = q;
    }
}

// ---------- stage kernels ----------
__global__ __launch_bounds__(256) void k_init(const float* __restrict__ vf,
                                              const int* __restrict__ coors,
                                              float* __restrict__ x,
                                              int* __restrict__ lut0,
                                              int* __restrict__ om1) {
    int i = blockIdx.x * 256 + threadIdx.x;
    if (i >= NN) return;
    x[i] = log10f(vf[i * 2]);
    int c1 = coors[i * 4 + 1], c2 = coors[i * 4 + 2], c3 = coors[i * 4 + 3];
    int e = 2 * c1 - 9, rg = 2 * c2, az = 2 * c3 + 149;
    atomicMax(&lut0[(e * S0_1 + rg) * S0_2 + az], i);
    int A[2], B[2], C[2]; int na, nb, nc;
    cand(e, S1_0, A, na); cand(rg, S1_1, B, nb); cand(az, S1_2, C, nc);
    for (int ia = 0; ia < na; ia++)
        for (int ib = 0; ib < nb; ib++)
            for (int ic = 0; ic < nc; ic++)
                om1[(A[ia] * S1_1 + B[ib]) * S1_2 + C[ic]] = 1;
}

// ---------- MFMA attention ----------
#define QS 40
__global__ __launch_bounds__(256, 1) void k_attn(float* __restrict__ x_io,
    const int* __restrict__ coors,
    const float* __restrict__ et, const float* __restrict__ at,
    const float* __restrict__ wq, const float* __restrict__ bq,
    const float* __restrict__ wk, const float* __restrict__ bk,
    const float* __restrict__ wv, const float* __restrict__ bv) {
    __shared__ float xin[KK * 7];
    __shared__ unsigned short ksh_h[256 * QS];
    __shared__ unsigned short ksh_l[256 * QS];
    __shared__ float vsh[256];
    const int r = blockIdx.x;
    const int t = threadIdx.x;
    const int w = t >> 6, ln = t & 63, l31 = ln & 31, lh = ln >> 5;

    for (int i = t; i < KK; i += 256) {
        int gi = r * KK + i;
        xin[i * 7 + 0] = x_io[gi];
        int c1 = coors[gi * 4 + 1], c3 = coors[gi * 4 + 3];
        xin[i * 7 + 1] = et[c1 * 3 + 0]; xin[i * 7 + 2] = et[c1 * 3 + 1]; xin[i * 7 + 3] = et[c1 * 3 + 2];
        xin[i * 7 + 4] = at[c3 * 3 + 0]; xin[i * 7 + 5] = at[c3 * 3 + 1]; xin[i * 7 + 6] = at[c3 * 3 + 2];
    }
    __syncthreads();

    union U8 { bf16x8 v; unsigned short u[8]; };

    for (int l = 0; l < 4; l++) {
        const float* wql = wq + l * 7 * 32; const float* bql = bq + l * 32;
        const float* wkl = wk + l * 7 * 32; const float* bkl = bk + l * 32;
        const float* wvl = wv + l * 7;      const float  bvl = bv[l];
        float qh_f[32], ql_f[32];
        if (t < KK) {
            float xi[7];
            #pragma unroll
            for (int ci = 0; ci < 7; ci++) xi[ci] = xin[t * 7 + ci];
            float av = bvl;
            #pragma unroll
            for (int ci = 0; ci < 7; ci++) av += xi[ci] * wvl[ci];
            vsh[t] = av;
            #pragma unroll
            for (int d = 0; d < 32; d++) {
                float aq = bql[d], ak = bkl[d];
                #pragma unroll
                for (int ci = 0; ci < 7; ci++) { aq += xi[ci] * wql[ci * 32 + d]; ak += xi[ci] * wkl[ci * 32 + d]; }
                aq *= ATT_SCALE;
                float h = b2f(f2b(aq));
                qh_f[d] = h; ql_f[d] = aq - h;
                unsigned short k16 = f2b(ak);
                ksh_h[t * QS + d] = k16;
                ksh_l[t * QS + d] = f2b(ak - b2f(k16));
            }
        } else {
            #pragma unroll
            for (int d = 0; d < 32; d++) {
                qh_f[d] = 0.f; ql_f[d] = 0.f;
                ksh_h[t * QS + d] = 0; ksh_l[t * QS + d] = 0;
            }
            vsh[t] = 0.f;
        }
        __syncthreads();

        U8 Bh[2][2], Bl[2][2];
        #pragma unroll
        for (int b = 0; b < 2; b++) {
            int src = b * 32 + l31;
            #pragma unroll
            for (int ks = 0; ks < 2; ks++) {
                #pragma unroll
                for (int j = 0; j < 8; j++) {
                    float h0 = __shfl(qh_f[ks * 16 + j],     src, 64);
                    float h1 = __shfl(qh_f[ks * 16 + 8 + j], src, 64);
                    float l0 = __shfl(ql_f[ks * 16 + j],     src, 64);
                    float l1 = __shfl(ql_f[ks * 16 + 8 + j], src, 64);
                    Bh[b][ks].u[j] = f2b(lh ? h1 : h0);
                    Bl[b][ks].u[j] = f2b(lh ? l1 : l0);
                }
            }
        }

        float m[2]  = {-1e30f, -1e30f};
        float den[2] = {0.f, 0.f};
        float num[2] = {0.f, 0.f};

        for (int mt = 0; mt < 8; mt++) {
            U8 Ah[2], Al[2];
            int krow = mt * 32 + l31;
            #pragma unroll
            for (int ks = 0; ks < 2; ks++) {
                Ah[ks].v = *(const bf16x8*)&ksh_h[krow * QS + ks * 16 + lh * 8];
                Al[ks].v = *(const bf16x8*)&ksh_l[krow * QS + ks * 16 + lh * 8];
            }
            float4 v4[4];
            #pragma unroll
            for (int c = 0; c < 4; c++)
                v4[c] = *(const float4*)&vsh[mt * 32 + 8 * c + 4 * lh];

            #pragma unroll
            for (int b = 0; b < 2; b++) {
                f32x16 acc;
                #pragma unroll
                for (int q = 0; q < 16; q++) acc[q] = 0.f;
                acc = __builtin_amdgcn_mfma_f32_32x32x16_bf16(Ah[0].v, Bh[b][0].v, acc, 0, 0, 0);
                acc = __builtin_amdgcn_mfma_f32_32x32x16_bf16(Ah[1].v, Bh[b][1].v, acc, 0, 0, 0);
                acc = __builtin_amdgcn_mfma_f32_32x32x16_bf16(Ah[0].v, Bl[b][0].v, acc, 0, 0, 0);
                acc = __builtin_amdgcn_mfma_f32_32x32x16_bf16(Ah[1].v, Bl[b][1].v, acc, 0, 0, 0);
                acc = __builtin_amdgcn_mfma_f32_32x32x16_bf16(Al[0].v, Bh[b][0].v, acc, 0, 0, 0);
                acc = __builtin_amdgcn_mfma_f32_32x32x16_bf16(Al[1].v, Bh[b][1].v, acc, 0, 0, 0);

                float s[16];
                #pragma unroll
                for (int rr = 0; rr < 16; rr++) {
                    s[rr] = acc[rr];
                    if (mt == 7) {
                        int key = 224 + (rr & 3) + 8 * (rr >> 2) + 4 * lh;
                        if (key >= KK) s[rr] = -1e30f;
                    }
                }
                float cm = s[0];
                #pragma unroll
                for (int rr = 1; rr < 16; rr++) cm = fmaxf(cm, s[rr]);
                cm = fmaxf(cm, __shfl_xor(cm, 32, 64));
                float mn = fmaxf(m[b], cm);
                float alpha = __expf(m[b] - mn);
                float dsum = 0.f, nsum = 0.f;
                #pragma unroll
                for (int rr = 0; rr < 16; rr++) {
                    float e = __expf(s[rr] - mn);
                    dsum += e;
                    nsum += e * ((&v4[rr >> 2].x)[rr & 3]);
                }
                den[b] = den[b] * alpha + dsum;
                num[b] = num[b] * alpha + nsum;
                m[b] = mn;
            }
        }
        __syncthreads();
        #pragma unroll
        for (int b = 0; b < 2; b++) {
            float dtot = den[b] + __shfl_xor(den[b], 32, 64);
            float ntot = num[b] + __shfl_xor(num[b], 32, 64);
            int q = (w * 2 + b) * 32 + l31;
            if (lh == 0 && q < KK) xin[q * 7] = ntot / dtot;
        }
        __syncthreads();
    }
    for (int i = t; i < KK; i += 256) x_io[r * KK + i] = xin[i * 7];
}

__global__ __launch_bounds__(256) void k_f0(const int* __restrict__ coors,
    const float* __restrict__ x,
    const float* __restrict__ w_in, const float* __restrict__ b_in,
    const float* __restrict__ gg, const float* __restrict__ gb,
    unsigned short* __restrict__ f0) {
    int i = blockIdx.x * 256 + threadIdx.x;
    if (i >= NN) return;
    int c1 = coors[i * 4 + 1], c2 = coors[i * 4 + 2], c3 = coors[i * 4 + 3];
    float fe0 = (float)(2 * c1 - 9), fe1 = (float)(2 * c2), fe2 = (float)(2 * c3 + 149), fe3 = x[i];
    float tv[16];
    #pragma unroll
    for (int c = 0; c < 16; c++)
        tv[c] = b_in[c] + fe0 * w_in[c] + fe1 * w_in[16 + c] + fe2 * w_in[32 + c] + fe3 * w_in[48 + c];
    #pragma unroll
    for (int g = 0; g < 8; g++) {
        float a = tv[2 * g], b = tv[2 * g + 1];
        float m = 0.5f * (a + b);
        float va = 0.5f * ((a - m) * (a - m) + (b - m) * (b - m));
        float inv = rsqrtf(va + 1e-5f);
        f0[i * 16 + 2 * g]     = f2b(fmaxf((a - m) * inv * gg[2 * g]     + gb[2 * g],     0.f));
        f0[i * 16 + 2 * g + 1] = f2b(fmaxf((b - m) * inv * gg[2 * g + 1] + gb[2 * g + 1], 0.f));
    }
}

__global__ __launch_bounds__(256) void k_blocksum(const int* __restrict__ om,
                                                  int* __restrict__ partials, int ncells) {
    __shared__ int sh[256];
    int t = threadIdx.x;
    int base = blockIdx.x * 1024 + t * 4;
    int s = 0;
    #pragma unroll
    for (int q = 0; q < 4; q++) s += (base + q < ncells) ? om[base + q] : 0;
    int incl = block_incl_scan(s, sh);
    if (t == 255) partials[blockIdx.x] = incl;
}

__global__ __launch_bounds__(256) void k_scanparts(int* __restrict__ partials, int nparts,
                                                   int* __restrict__ pcnt, int cap) {
    __shared__ int sh[256];
    __shared__ int tot;
    int t = threadIdx.x;
    int chunk = (nparts + 255) / 256;
    int beg = t * chunk;
    int vals[8];
    int s = 0;
    #pragma unroll
    for (int i = 0; i < 8; i++) {
        if (i < chunk) {
            int ix = beg + i;
            int x = (ix < nparts) ? partials[ix] : 0;
            vals[i] = x; s += x;
        }
    }
    int incl = block_incl_scan(s, sh);
    int excl = incl - s;
    if (t == 255) tot = incl;
    int run = excl;
    #pragma unroll
    for (int i = 0; i < 8; i++) {
        if (i < chunk) {
            int ix = beg + i;
            if (ix < nparts) { partials[ix] = run; run += vals[i]; }
        }
    }
    __syncthreads();
    if (t == 0) *pcnt = min(tot, cap);
}

__global__ __launch_bounds__(256) void k_emit(const int* __restrict__ om,
                                              const int* __restrict__ partials,
                                              int* __restrict__ oc,
                                              int ncells, int D1, int D2, int cap) {
    __shared__ int sh[256];
    int t = threadIdx.x;
    int base = blockIdx.x * 1024 + t * 4;
    int v[4]; int s = 0;
    #pragma unroll
    for (int q = 0; q < 4; q++) { v[q] = (base + q < ncells) ? om[base + q] : 0; s += v[q]; }
    int incl = block_incl_scan(s, sh);
    int run = partials[blockIdx.x] + (incl - s);
    int D12 = D1 * D2;
    #pragma unroll
    for (int q = 0; q < 4; q++) {
        if (v[q]) {
            if (run < cap) {
                int lin = base + q;
                int i0 = lin / D12;
                int r2 = lin - i0 * D12;
                int i1 = r2 / D2;
                int i2 = r2 - i1 * D2;
                oc[run * 3] = i0; oc[run * 3 + 1] = i1; oc[run * 3 + 2] = i2;
            }
            run++;
        }
    }
}

__global__ __launch_bounds__(256) void k_lutscatter(const int* __restrict__ oc,
                                                    const int* __restrict__ pc,
                                                    int* __restrict__ lut, int D1, int D2) {
    int j = blockIdx.x * 256 + threadIdx.x;
    if (j >= *pc) return;
    lut[(oc[j * 3] * D1 + oc[j * 3 + 1]) * D2 + oc[j * 3 + 2]] = j;
}

__global__ __launch_bounds__(256) void k_lutscatter2(const int* __restrict__ oc,
                                                     const int* __restrict__ pc,
                                                     int* __restrict__ lut,
                                                     int* __restrict__ lut_t) {
    int j = blockIdx.x * 256 + threadIdx.x;
    if (j >= *pc) return;
    int a = oc[j * 3], b = oc[j * 3 + 1], c = oc[j * 3 + 2];
    lut[(a * S2_1 + b) * S2_2 + c] = j;
    lut_t[(c * S2_1 + b) * S2_0 + a] = j;
}

__global__ __launch_bounds__(256) void k_mask2(const int* __restrict__ oc,
                                               const int* __restrict__ pc,
                                               int* __restrict__ om) {
    int j = blockIdx.x * 256 + threadIdx.x;
    if (j >= *pc) return;
    int p0 = oc[j * 3], p1 = oc[j * 3 + 1], p2 = oc[j * 3 + 2];
    int A[2], B[2], C[2]; int na, nb, nc;
    cand(p0, S2_0, A, na); cand(p1, S2_1, B, nb); cand(p2, S2_2, C, nc);
    for (int ia = 0; ia < na; ia++)
        for (int ib = 0; ib < nb; ib++)
            for (int ic = 0; ic < nc; ic++)
                om[(A[ia] * S2_1 + B[ib]) * S2_2 + C[ic]] = 1;
}

// ---------- weight pre-pack into MFMA B-fragment order ----------
__global__ __launch_bounds__(256) void k_prepack(const float* __restrict__ w,
        unsigned short* __restrict__ wp, int nk, int cin, int cout) {
    int tid = blockIdx.x * 256 + threadIdx.x;
    int tot = nk * cin * cout;
    if (tid >= tot) return;
    int co = tid % cout; int rest = tid / cout; int ci = rest % cin; int kk = rest / cin;
    int ks = ci >> 4, kr = ci & 15, half = kr >> 3, j = kr & 7;
    int nt = co >> 5, cl = co & 31, lane = half * 32 + cl;
    wp[((((size_t)kk * (cin >> 4) + ks) * (cout >> 5) + nt) * 64 + lane) * 8 + j] = f2b(w[tid]);
}

// ---------- neighbor-index table (level 2) ----------
template<bool DOWN, int SD0, int SD1, int SD2>
__global__ __launch_bounds__(256) void k_nbidx(const int* __restrict__ oc,
        const int* __restrict__ pc, const int* __restrict__ lut,
        int* __restrict__ nb, int NBx, int ZR) {
    int gid = blockIdx.x * 256 + threadIdx.x;
    if (gid >= 27 * NBx) return;
    int k = gid / NBx, j = gid - k * NBx;
    int idx = ZR;
    if (j < *pc) {
        int dx = k / 9 - 1, dy = (k / 3) % 3 - 1, dz = k % 3 - 1;
        int x = oc[j * 3], y = oc[j * 3 + 1], z = oc[j * 3 + 2];
        if (DOWN) { x = 2 * x + dx; y = 2 * y + dy; z = 2 * z + dz; }
        else      { x += dx; y += dy; z += dz; }
        if ((unsigned)x < (unsigned)SD0 && (unsigned)y < (unsigned)SD1 && (unsigned)z < (unsigned)SD2) {
            int v = lut[(x * SD1 + y) * SD2 + z];
            if (v >= 0) idx = v;
        }
    }
    nb[gid] = idx;
}

// ---------- async DMA MFMA gather-conv, 512 threads (8 waves) ----------
// ROWS x COUT per block. A staged via global_load_lds (16B/lane, double-
// buffered LDS, zero data VGPRs). Per K-step issue ORDER (the R9 fix):
//   barrier -> batched breg[KS] B-loads (OLDEST vmcnt) -> DMAs for k+1 ->
//   nb prefetch -> MFMA section.
// MFMA waits on breg become vmcnt(N>0): the DMAs stay in flight through
// the whole MFMA section; only the next barrier's vmcnt(0) drains them.
// Wave grid: NTT col-groups x (8/NTT) row-groups; TM = ROWS/32/(8/NTT).
// XOR swizzle (chunk c of row r at slot c^((r>>SH)&(CPR-1))) keeps
// ds_read/ds_write bank-spread with the DMA's forced lane-linear layout.
// MODE 0: bn+relu  MODE 1: bn+res+relu  MODE 2: bias+gn16+relu -> fo_t
template<int CIN, int COUT, int ROWS, int SD0, int SD1, int SD2, bool DOWN, int MODE, bool TAB>
__global__ __launch_bounds__(512, 4)
void k_aconv(const unsigned short* __restrict__ fin, const int* __restrict__ lut,
             const int* __restrict__ nb, int NBx,
             const int* __restrict__ oc, const int* __restrict__ pc,
             const unsigned short* __restrict__ wp,
             const float* __restrict__ p0, const float* __restrict__ p1,
             const float* __restrict__ p2,
             const unsigned short* __restrict__ res, void* __restrict__ fout_,
             int ZR) {
    constexpr int KS  = CIN / 16;
    constexpr int NTT = COUT / 32;
    constexpr int NRG = 8 / NTT;             // row groups
    constexpr int TM  = (ROWS / 32) / NRG;
    constexpr int CPR = CIN / 8;             // 16B chunks per row
    constexpr int RPI = 64 / CPR;            // rows per DMA instruction
    constexpr int RPW = ROWS / 8;            // rows staged per wave
    constexpr int IPW = RPW / RPI;           // DMA instructions per wave
    constexpr int SH  = (CPR == 16) ? 0 : ((CPR == 4) ? 1 : 2);
    __shared__ unsigned short sA[2 * ROWS * CIN];

    const int n = *pc;
    const int blk = xcd_swizzle(blockIdx.x, gridDim.x);
    const int j0 = blk * ROWS;
    if (j0 >= n) return;
    const int t = threadIdx.x;
    const int w = t >> 6, ln = t & 63, l31 = ln & 31, lh = ln >> 5;
    const int colt = w & (NTT - 1);
    const int rowb = (w / NTT) * TM * 32;

    // this lane's staging rows (one per DMA instruction)
    const int lrow = ln / CPR;
    const int slot = ln % CPR;
    int myrow[IPW];
    #pragma unroll
    for (int i = 0; i < IPW; i++) myrow[i] = w * RPW + i * RPI + lrow;

    // inline-lut coords (level-1)
    int cxa[IPW], cya[IPW], cza[IPW];
    if (!TAB) {
        #pragma unroll
        for (int i = 0; i < IPW; i++) {
            int j = j0 + myrow[i];
            if (j < n) { cxa[i] = oc[j * 3]; cya[i] = oc[j * 3 + 1]; cza[i] = oc[j * 3 + 2]; }
            else       { cxa[i] = -1000000; cya[i] = -1000000; cza[i] = -1000000; }
        }
    }

    auto fetchIdx = [&](int kk, int* ir) {
        if (TAB) {
            #pragma unroll
            for (int i = 0; i < IPW; i++)
                ir[i] = nb[kk * NBx + j0 + myrow[i]];
        } else {
            int dx = kk / 9 - 1, dy = (kk / 3) % 3 - 1, dz = kk % 3 - 1;
            #pragma unroll
            for (int i = 0; i < IPW; i++) {
                int x, y, z;
                if (DOWN) { x = 2 * cxa[i] + dx; y = 2 * cya[i] + dy; z = 2 * cza[i] + dz; }
                else      { x = cxa[i] + dx; y = cya[i] + dy; z = cza[i] + dz; }
                int idx = -1;
                if ((unsigned)x < (unsigned)SD0 && (unsigned)y < (unsigned)SD1 && (unsigned)z < (unsigned)SD2)
                    idx = lut[(x * SD1 + y) * SD2 + z];
                ir[i] = idx < 0 ? ZR : idx;
            }
        }
    };

    auto stage = [&](int buf, const int* ir) {
        #pragma unroll
        for (int i = 0; i < IPW; i++) {
            unsigned short* ldsb = &sA[(size_t)buf * ROWS * CIN + (w * RPW + i * RPI) * CIN]; // wave-uniform
            int g = (myrow[i] >> SH) & (CPR - 1);
            const unsigned short* gp = fin + (size_t)ir[i] * CIN + ((slot ^ g) * 8);
            gld_lds16(ldsb, gp);
        }
    };

    f32x16 acc[TM];
    #pragma unroll
    for (int a = 0; a < TM; a++)
        #pragma unroll
        for (int q = 0; q < 16; q++) acc[a][q] = 0.f;

    int irn[IPW];
    fetchIdx(0, irn);
    stage(0, irn);
    fetchIdx(1, irn);

    for (int k = 0; k < 27; k++) {
        __syncthreads();                     // vmcnt(0) drain precedes barrier
        // B fragments FIRST (oldest in vmcnt queue)
        const unsigned short* wk = wp + (size_t)k * KS * NTT * 512;
        bf16x8 breg[KS];
        #pragma unroll
        for (int ks = 0; ks < KS; ks++)
            breg[ks] = *(const bf16x8*)(wk + ((size_t)(ks * NTT + colt) * 64 + ln) * 8);
        // then DMAs for k+1 (stay in flight over the MFMA section)
        if (k < 26) {
            stage((k + 1) & 1, irn);
            fetchIdx(k + 2 <= 26 ? k + 2 : 26, irn);
        }
        const unsigned short* bufA = &sA[(size_t)(k & 1) * ROWS * CIN];
        #pragma unroll
        for (int ks = 0; ks < KS; ks++) {
            #pragma unroll
            for (int a = 0; a < TM; a++) {
                int r = rowb + a * 32 + l31;
                int c = ks * 2 + lh;
                int sl = c ^ ((r >> SH) & (CPR - 1));
                bf16x8 afr = *(const bf16x8*)(bufA + (size_t)r * CIN + sl * 8);
                acc[a] = __builtin_amdgcn_mfma_f32_32x32x16_bf16(afr, breg[ks], acc[a], 0, 0, 0);
            }
        }
    }

    const int co = colt * 32 + l31;
    if (MODE != 2) {
        unsigned short* fout = (unsigned short*)fout_;
        float g_ = p0[co], bb_ = p0[COUT + co], m_ = p0[2 * COUT + co];
        float iv = rsqrtf(p0[3 * COUT + co] + 1e-3f);
        #pragma unroll
        for (int a = 0; a < TM; a++) {
            #pragma unroll
            for (int r = 0; r < 16; r++) {
                int j = j0 + rowb + a * 32 + (r & 3) + 8 * (r >> 2) + 4 * lh;
                if (j < n) {
                    float y = (acc[a][r] - m_) * iv * g_ + bb_;
                    if (MODE == 1) y += b2f(res[(size_t)j * COUT + co]);
                    fout[(size_t)j * COUT + co] = f2b(fmaxf(y, 0.f));
                }
            }
        }
    } else {
        float* fo_t = (float*)fout_;
        float bias = p0[co], gg_ = p1[co], gb_ = p2[co];
        #pragma unroll
        for (int a = 0; a < TM; a++) {
            #pragma unroll
            for (int r = 0; r < 16; r++) {
                int j = j0 + rowb + a * 32 + (r & 3) + 8 * (r >> 2) + 4 * lh;
                float y = acc[a][r] + bias;
                float s = y;
                s += __shfl_xor(s, 1, 8);
                s += __shfl_xor(s, 2, 8);
                s += __shfl_xor(s, 4, 8);
                float m = s * 0.125f;
                float d = y - m;
                float q2 = d * d;
                q2 += __shfl_xor(q2, 1, 8);
                q2 += __shfl_xor(q2, 2, 8);
                q2 += __shfl_xor(q2, 4, 8);
                float var = q2 * 0.125f;
                float o = fmaxf(d * rsqrtf(var + 1e-5f) * gg_ + gb_, 0.f);
                fo_t[(size_t)co * FOP + j] = o;
            }
        }
    }
}

// ---------- dense output scatter (coalesced reads AND writes) ----------
__global__ __launch_bounds__(256) void k_scatter(const float* __restrict__ fo_t,
                                                 const int* __restrict__ lut2t,
                                                 float* __restrict__ dout) {
    int gid = blockIdx.x * 256 + threadIdx.x;
    int cell = gid % CELLS2;
    int co = gid / CELLS2;
    int idx = lut2t[cell];
    float v = 0.f;
    if (idx >= 0) v = fo_t[(size_t)co * FOP + idx];
    dout[gid] = v;
}

// ---------- host ----------
extern "C" void kernel_launch(void* const* d_in, const int* in_sizes, int n_in,
                              void* d_out, int out_size, void* d_ws, size_t ws_size,
                              hipStream_t stream) {
    const float* vf    = (const float*)d_in[0];
    const int*   coors = (const int*)d_in[1];
    const float* et    = (const float*)d_in[3];
    const float* at    = (const float*)d_in[4];
    const float* wq    = (const float*)d_in[5];
    const float* bq    = (const float*)d_in[6];
    const float* wk_   = (const float*)d_in[7];
    const float* bk    = (const float*)d_in[8];
    const float* wv    = (const float*)d_in[9];
    const float* bv    = (const float*)d_in[10];
    const float* w_in  = (const float*)d_in[11];
    const float* b_in  = (const float*)d_in[12];
    const float* gin_g = (const float*)d_in[13];
    const float* gin_b = (const float*)d_in[14];
    const float* w_d1  = (const float*)d_in[15];
    const float* bn_d1 = (const float*)d_in[16];
    const float* w_r1  = (const float*)d_in[17];
    const float* bn_r1 = (const float*)d_in[18];
    const float* w_d2  = (const float*)d_in[19];
    const float* bn_d2 = (const float*)d_in[20];
    const float* w_r2  = (const float*)d_in[21];
    const float* bn_r2 = (const float*)d_in[22];
    const float* w_out = (const float*)d_in[23];
    const float* b_out = (const float*)d_in[24];
    const float* gout_g= (const float*)d_in[25];
    const float* gout_b= (const float*)d_in[26];

    char* ws = (char*)d_ws;
    size_t cur = 0;
    auto take = [&](size_t bytes) -> char* {
        char* p = ws + cur;
        cur += (bytes + 255) & ~(size_t)255;
        return p;
    };
    size_t usz1 = (size_t)4194304 + (size_t)CELLS0 * 4;
    size_t usz2 = (size_t)17694720 + (size_t)128 * FOP * 4;
    char* U = take(usz1 > usz2 ? usz1 : usz2);
    float*          x_att = (float*)U;
    unsigned short* f0    = (unsigned short*)(U + 262144);
    int*            lut0  = (int*)(U + 4194304);
    unsigned short* fB1   = (unsigned short*)U;
    unsigned short* fA2   = (unsigned short*)U;
    unsigned short* fB2   = (unsigned short*)(U + 17694720);
    float*          fo_t  = (float*)(U + 17694720);

    int*   om1      = (int*)take((size_t)CELLS1 * 4);
    int*   om2      = (int*)take((size_t)CELLS2 * 4);
    int*   partials = (int*)take(8192);
    int*   cnt      = (int*)take(256);
    int*   oc1      = (int*)take((size_t)CAP1 * 3 * 4);
    int*   oc2      = (int*)take((size_t)CAP2 * 3 * 4);
    unsigned short* fA1 = (unsigned short*)take((size_t)(CAP1 + 1) * C1 * 2);
    int*   lut1     = (int*)take((size_t)CELLS1 * 4);
    int*   lut2     = (int*)take((size_t)CELLS2 * 4);
    int*   lut2t    = (int*)take((size_t)CELLS2 * 4);
    int*   nb_d2    = (int*)take((size_t)27 * NB2X * 4);
    int*   nb_r2    = (int*)take((size_t)27 * NB2X * 4);
    unsigned short* wp_d1  = (unsigned short*)take((size_t)27 * 16 * 32 * 2);
    unsigned short* wp_r1  = (unsigned short*)take((size_t)108 * 32 * 32 * 2);
    unsigned short* wp_d2  = (unsigned short*)take((size_t)27 * 32 * 128 * 2);
    unsigned short* wp_r2  = (unsigned short*)take((size_t)108 * 128 * 128 * 2);
    unsigned short* wp_out = (unsigned short*)take((size_t)27 * 128 * 128 * 2);

    hipMemsetAsync(lut0, 0xFF, (size_t)CELLS0 * 4, stream);
    hipMemsetAsync(om1, 0, (size_t)CELLS1 * 4, stream);
    hipMemsetAsync(om2, 0, (size_t)CELLS2 * 4, stream);
    hipMemsetAsync(lut1, 0xFF, (size_t)CELLS1 * 4, stream);
    hipMemsetAsync(lut2, 0xFF, (size_t)CELLS2 * 4, stream);
    hipMemsetAsync(lut2t, 0xFF, (size_t)CELLS2 * 4, stream);
    hipMemsetAsync(f0 + (size_t)NN * 16, 0, 32, stream);        // f0 zero row (ZR=NN)
    hipMemsetAsync(fA1 + (size_t)CAP1 * C1, 0, 64, stream);     // fA1 zero row (ZR=CAP1)

    const int gN  = (NN + 255) / 256;
    const int gB1 = CELLS1 / 1024;
    const int gB2 = CELLS2 / 1024;
    const int gM1 = (CAP1 + 255) / 256;   // 256-row blocks -> 1368
    const int gM2 = (CAP2 + 127) / 128;   // 128-row blocks -> 540
    const int gS1 = (CAP1 + 255) / 256;
    const int gS2 = (CAP2 + 255) / 256;
    const int gNB = (27 * NB2X + 255) / 256;

    k_prepack<<<(27*16*32   + 255)/256, 256, 0, stream>>>(w_d1,  wp_d1, 27, 16, 32);
    k_prepack<<<(108*32*32  + 255)/256, 256, 0, stream>>>(w_r1,  wp_r1, 108, 32, 32);
    k_prepack<<<(27*32*128  + 255)/256, 256, 0, stream>>>(w_d2,  wp_d2, 27, 32, 128);
    k_prepack<<<(108*128*128+ 255)/256, 256, 0, stream>>>(w_r2,  wp_r2, 108, 128, 128);
    k_prepack<<<(27*128*128 + 255)/256, 256, 0, stream>>>(w_out, wp_out, 27, 128, 128);

    k_init<<<gN, 256, 0, stream>>>(vf, coors, x_att, lut0, om1);
    k_attn<<<NRR, 256, 0, stream>>>(x_att, coors, et, at, wq, bq, wk_, bk, wv, bv);
    k_f0<<<gN, 256, 0, stream>>>(coors, x_att, w_in, b_in, gin_g, gin_b, f0);

    k_blocksum<<<gB1, 256, 0, stream>>>(om1, partials, CELLS1);
    k_scanparts<<<1, 256, 0, stream>>>(partials, gB1, cnt, CAP1);
    k_emit<<<gB1, 256, 0, stream>>>(om1, partials, oc1, CELLS1, S1_1, S1_2, CAP1);

    // down conv 1 (16 -> 32), inline lut0, 256-row blocks
    k_aconv<16, 32, 256, S0_0, S0_1, S0_2, true, 0, false><<<gM1, 512, 0, stream>>>(
        f0, lut0, nullptr, 0, oc1, cnt, wp_d1, bn_d1, nullptr, nullptr, nullptr, fA1, NN);
    k_lutscatter<<<gS1, 256, 0, stream>>>(oc1, cnt, lut1, S1_1, S1_2);
    hipMemsetAsync(fB1 + (size_t)CAP1 * C1, 0, 64, stream);     // fB1 zero row

    // resblocks level 1 (32 ch), inline lut1, 256-row blocks
    k_aconv<32, 32, 256, S1_0, S1_1, S1_2, false, 0, false><<<gM1, 512, 0, stream>>>(
        fA1, lut1, nullptr, 0, oc1, cnt, wp_r1 + 0 * 27648, bn_r1 + 0 * 128, nullptr, nullptr, nullptr, fB1, CAP1);
    k_aconv<32, 32, 256, S1_0, S1_1, S1_2, false, 1, false><<<gM1, 512, 0, stream>>>(
        fB1, lut1, nullptr, 0, oc1, cnt, wp_r1 + 1 * 27648, bn_r1 + 1 * 128, nullptr, nullptr, fA1, fA1, CAP1);
    k_aconv<32, 32, 256, S1_0, S1_1, S1_2, false, 0, false><<<gM1, 512, 0, stream>>>(
        fA1, lut1, nullptr, 0, oc1, cnt, wp_r1 + 2 * 27648, bn_r1 + 2 * 128, nullptr, nullptr, nullptr, fB1, CAP1);
    k_aconv<32, 32, 256, S1_0, S1_1, S1_2, false, 1, false><<<gM1, 512, 0, stream>>>(
        fB1, lut1, nullptr, 0, oc1, cnt, wp_r1 + 3 * 27648, bn_r1 + 3 * 128, nullptr, nullptr, fA1, fA1, CAP1);

    k_mask2<<<gS1, 256, 0, stream>>>(oc1, cnt, om2);
    k_blocksum<<<gB2, 256, 0, stream>>>(om2, partials, CELLS2);
    k_scanparts<<<1, 256, 0, stream>>>(partials, gB2, cnt + 1, CAP2);
    k_emit<<<gB2, 256, 0, stream>>>(om2, partials, oc2, CELLS2, S2_1, S2_2, CAP2);

    // level-2 neighbor tables + zero rows
    k_nbidx<true, S1_0, S1_1, S1_2><<<gNB, 256, 0, stream>>>(oc2, cnt + 1, lut1, nb_d2, NB2X, CAP1);
    hipMemsetAsync(fA2 + (size_t)CAP2 * C2, 0, 256, stream);
    hipMemsetAsync(fB2 + (size_t)CAP2 * C2, 0, 256, stream);

    // down conv 2 (32 -> 128), nb table, 128-row blocks
    k_aconv<32, 128, 128, S1_0, S1_1, S1_2, true, 0, true><<<gM2, 512, 0, stream>>>(
        fA1, nullptr, nb_d2, NB2X, oc2, cnt + 1, wp_d2, bn_d2, nullptr, nullptr, nullptr, fA2, CAP1);
    k_lutscatter2<<<gS2, 256, 0, stream>>>(oc2, cnt + 1, lut2, lut2t);
    k_nbidx<false, S2_0, S2_1, S2_2><<<gNB, 256, 0, stream>>>(oc2, cnt + 1, lut2, nb_r2, NB2X, CAP2);

    const size_t wr2s = (size_t)27 * 128 * 128;
    k_aconv<128, 128, 128, S2_0, S2_1, S2_2, false, 0, true><<<gM2, 512, 0, stream>>>(
        fA2, nullptr, nb_r2, NB2X, oc2, cnt + 1, wp_r2 + 0 * wr2s, bn_r2 + 0 * 512, nullptr, nullptr, nullptr, fB2, CAP2);
    k_aconv<128, 128, 128, S2_0, S2_1, S2_2, false, 1, true><<<gM2, 512, 0, stream>>>(
        fB2, nullptr, nb_r2, NB2X, oc2, cnt + 1, wp_r2 + 1 * wr2s, bn_r2 + 1 * 512, nullptr, nullptr, fA2, fA2, CAP2);
    k_aconv<128, 128, 128, S2_0, S2_1, S2_2, false, 0, true><<<gM2, 512, 0, stream>>>(
        fA2, nullptr, nb_r2, NB2X, oc2, cnt + 1, wp_r2 + 2 * wr2s, bn_r2 + 2 * 512, nullptr, nullptr, nullptr, fB2, CAP2);
    k_aconv<128, 128, 128, S2_0, S2_1, S2_2, false, 1, true><<<gM2, 512, 0, stream>>>(
        fB2, nullptr, nb_r2, NB2X, oc2, cnt + 1, wp_r2 + 3 * wr2s, bn_r2 + 3 * 512, nullptr, nullptr, fA2, fA2, CAP2);

    k_aconv<128, 128, 128, S2_0, S2_1, S2_2, false, 2, true><<<gM2, 512, 0, stream>>>(
        fA2, nullptr, nb_r2, NB2X, oc2, cnt + 1, wp_out, b_out, gout_g, gout_b, nullptr, fo_t, CAP2);
    k_scatter<<<(S2_0 * S2_1 * S2_2 * 128) / 256, 256, 0, stream>>>(fo_t, lut2t, (float*)d_out);
}